// Round 2
// baseline (917.271 us; speedup 1.0000x reference)
//
#include <hip/hip_runtime.h>
#include <hip/hip_bf16.h>

#define WS_ALIGN(x) (((x) + 255) & ~(size_t)255)

// ---------------- embedding gather ----------------
__global__ void embed_kernel(const int* __restrict__ x, const float* __restrict__ emb,
                             float* __restrict__ h, int n) {
    int t = blockIdx.x * blockDim.x + threadIdx.x;
    if (t >= n * 128) return;
    int node = t >> 7, d = t & 127;
    h[t] = emb[(x[node * 11] << 7) | d];
}

// ---------------- generic small GEMM: out[n,NOUT] = A[n,K] @ W[K,NOUT] (+bias)(+relu) ----------------
template <int K, int NOUT, int RPT>
__global__ __launch_bounds__(256) void gemm_rm(const float* __restrict__ A, const float* __restrict__ W,
                                               const float* __restrict__ bias, float* __restrict__ out,
                                               int n, int relu) {
    constexpr int SLOTS = 256 / NOUT;
    constexpr int RPB = SLOTS * RPT;
    int j = threadIdx.x % NOUT;
    int slot = threadIdx.x / NOUT;
    int base = blockIdx.x * RPB + slot * RPT;
    float acc[RPT];
#pragma unroll
    for (int r = 0; r < RPT; ++r) acc[r] = 0.f;
#pragma unroll 4
    for (int k = 0; k < K; ++k) {
        float wv = W[k * NOUT + j];
#pragma unroll
        for (int r = 0; r < RPT; ++r) {
            int nr = base + r;
            float a = (nr < n) ? A[nr * K + k] : 0.f;
            acc[r] += a * wv;
        }
    }
    float b = bias ? bias[j] : 0.f;
#pragma unroll
    for (int r = 0; r < RPT; ++r) {
        int nr = base + r;
        if (nr < n) {
            float v = acc[r] + b;
            if (relu) v = fmaxf(v, 0.f);
            out[nr * NOUT + j] = v;
        }
    }
}

// ---------------- in-degree count ----------------
__global__ void count_kernel(const int* __restrict__ dst, int* __restrict__ cnt, int e) {
    int t = blockIdx.x * blockDim.x + threadIdx.x;
    if (t < e) atomicAdd(&cnt[dst[t]], 1);
}

// ---------------- dinv = rsqrt(in_deg + 1)  (self loop included) ----------------
__global__ void dinv_kernel(const int* __restrict__ cnt, float* __restrict__ dinv, int n) {
    int t = blockIdx.x * blockDim.x + threadIdx.x;
    if (t < n) dinv[t] = rsqrtf((float)cnt[t] + 1.0f);
}

// ---------------- exclusive scan of cnt -> rowptr (single block) ----------------
__global__ __launch_bounds__(1024) void scan_kernel(const int* __restrict__ cnt, int* __restrict__ rowptr, int n) {
    __shared__ int wsum[16];
    __shared__ int carry_s;
    int tid = threadIdx.x, lane = tid & 63, wid = tid >> 6;
    if (tid == 0) carry_s = 0;
    __syncthreads();
    for (int base = 0; base < n; base += 1024) {
        int i = base + tid;
        int v = (i < n) ? cnt[i] : 0;
        int s = v;
#pragma unroll
        for (int o = 1; o < 64; o <<= 1) {
            int t = __shfl_up(s, o);
            if (lane >= o) s += t;
        }
        if (lane == 63) wsum[wid] = s;
        __syncthreads();
        if (tid == 0) {
            int acc = carry_s;
#pragma unroll
            for (int w = 0; w < 16; ++w) { int t = wsum[w]; wsum[w] = acc; acc += t; }
            carry_s = acc;
        }
        __syncthreads();
        int off = wsum[wid];
        if (i < n) rowptr[i] = off + s - v;
        __syncthreads();
    }
    if (tid == 0) rowptr[n] = carry_s;
}

// ---------------- CSR fill (store src node id per incoming edge) ----------------
__global__ void fill_kernel(const int* __restrict__ src, const int* __restrict__ dst,
                            const int* __restrict__ rowptr, int* __restrict__ fillcnt,
                            int* __restrict__ csr_src, int e) {
    int t = blockIdx.x * blockDim.x + threadIdx.x;
    if (t >= e) return;
    int d = dst[t];
    int pos = rowptr[d] + atomicAdd(&fillcnt[d], 1);
    csr_src[pos] = src[t];
}

// ---------------- GCN aggregate: out = relu(sum_{s->n} hl[s]*dinv[s]*dinv[n] + hl[n]*dinv[n]^2 + b) ----------------
__global__ __launch_bounds__(256) void gcn_agg_kernel(const float* __restrict__ hl, const float* __restrict__ dinv,
                                                      const int* __restrict__ rowptr, const int* __restrict__ csr_src,
                                                      const float* __restrict__ bias, float* __restrict__ out, int n) {
    int wave = threadIdx.x >> 6, lane = threadIdx.x & 63;
    int node = blockIdx.x * 4 + wave;
    if (node >= n) return;
    float dn = dinv[node];
    const float2* selfrow = (const float2*)(hl + (size_t)node * 128);
    float2 sv = selfrow[lane];
    float a0 = sv.x * dn * dn, a1 = sv.y * dn * dn;
    int beg = rowptr[node], end = rowptr[node + 1];
    for (int idx = beg; idx < end; ++idx) {
        int s = csr_src[idx];
        float w = dinv[s] * dn;
        float2 hv = ((const float2*)(hl + (size_t)s * 128))[lane];
        a0 += hv.x * w;
        a1 += hv.y * w;
    }
    int d0 = lane * 2;
    a0 = fmaxf(a0 + bias[d0], 0.f);
    a1 = fmaxf(a1 + bias[d0 + 1], 0.f);
    ((float2*)(out + (size_t)node * 128))[lane] = make_float2(a0, a1);
}

// ---------------- MLA attention: one wave per dst node, online softmax, 8 heads x 16 dims ----------------
__global__ __launch_bounds__(256) void attn_kernel(const float* __restrict__ q, const float* __restrict__ kf,
                                                   const float* __restrict__ vf, const int* __restrict__ rowptr,
                                                   const int* __restrict__ csr_src, float* __restrict__ agg, int n) {
    int wave = threadIdx.x >> 6, lane = threadIdx.x & 63;
    int node = blockIdx.x * 4 + wave;
    if (node >= n) return;
    float2 qv = ((const float2*)(q + (size_t)node * 128))[lane];
    int beg = rowptr[node], end = rowptr[node + 1];
    float m = -INFINITY, den = 0.f, a0 = 0.f, a1 = 0.f;
    for (int idx = beg; idx < end; ++idx) {
        int s = csr_src[idx];
        float2 kv = ((const float2*)(kf + (size_t)s * 128))[lane];
        float part = qv.x * kv.x + qv.y * kv.y;
        part += __shfl_xor(part, 1);
        part += __shfl_xor(part, 2);
        part += __shfl_xor(part, 4);
        float score = part * 0.25f; // 1/sqrt(16)
        float mnew = fmaxf(m, score);
        float corr = __expf(m - mnew);   // exp(-inf)=0 on first iter
        float p = __expf(score - mnew);
        den = den * corr + p;
        float2 vv = ((const float2*)(vf + (size_t)s * 128))[lane];
        a0 = a0 * corr + p * vv.x;
        a1 = a1 * corr + p * vv.y;
        m = mnew;
    }
    float r = (end > beg) ? 1.f / fmaxf(den, 1e-16f) : 0.f;
    ((float2*)(agg + (size_t)node * 128))[lane] = make_float2(a0 * r, a1 * r);
}

// ---------------- LN + relu + residual + pooled atomic add ----------------
__global__ __launch_bounds__(256) void ln_pool_kernel(const float* __restrict__ attn, const float* __restrict__ res,
                                                      const float* __restrict__ g, const float* __restrict__ b,
                                                      const int* __restrict__ batch, float* __restrict__ pooled, int n) {
    int wave = threadIdx.x >> 6, lane = threadIdx.x & 63;
    int node = blockIdx.x * 4 + wave;
    if (node >= n) return;
    float2 x = ((const float2*)(attn + (size_t)node * 128))[lane];
    float2 rr = ((const float2*)(res + (size_t)node * 128))[lane];
    x.x += rr.x;
    x.y += rr.y;
    float s = x.x + x.y;
#pragma unroll
    for (int o = 1; o < 64; o <<= 1) s += __shfl_xor(s, o);
    float mu = s * (1.f / 128.f);
    float dx = x.x - mu, dy = x.y - mu;
    float vs = dx * dx + dy * dy;
#pragma unroll
    for (int o = 1; o < 64; o <<= 1) vs += __shfl_xor(vs, o);
    float rstd = rsqrtf(vs * (1.f / 128.f) + 1e-5f);
    int d0 = lane * 2;
    float y0 = fmaxf(dx * rstd * g[d0] + b[d0], 0.f);
    float y1 = fmaxf(dy * rstd * g[d0 + 1] + b[d0 + 1], 0.f);
    int gid = batch[node];
    atomicAdd(&pooled[(size_t)gid * 128 + d0], y0);
    atomicAdd(&pooled[(size_t)gid * 128 + d0 + 1], y1);
}

// ---------------- final FC: out[g,19] = pooled[g,128] @ fc_w + fc_b ----------------
__global__ void fc_kernel(const float* __restrict__ pooled, const float* __restrict__ w,
                          const float* __restrict__ bias, float* __restrict__ out, int gcount) {
    int idx = blockIdx.x * blockDim.x + threadIdx.x;
    if (idx >= gcount * 19) return;
    int gi = idx / 19, j = idx % 19;
    float acc = bias[j];
#pragma unroll 8
    for (int k = 0; k < 128; ++k) acc += pooled[(size_t)gi * 128 + k] * w[k * 19 + j];
    out[idx] = acc;
}

extern "C" void kernel_launch(void* const* d_in, const int* in_sizes, int n_in,
                              void* d_out, int out_size, void* d_ws, size_t ws_size,
                              hipStream_t stream) {
    const int* x = (const int*)d_in[0];
    const int* edge_index = (const int*)d_in[1];
    const int* batch = (const int*)d_in[2];
    const float* node_emb = (const float*)d_in[3];
    const float* gcn_w = (const float*)d_in[4];
    const float* gcn_b = (const float*)d_in[5];
    const float* qd_w = (const float*)d_in[6];
    const float* qd_b = (const float*)d_in[7];
    const float* qu_w = (const float*)d_in[8];
    const float* qu_b = (const float*)d_in[9];
    const float* kvd_w = (const float*)d_in[10];
    const float* kvd_b = (const float*)d_in[11];
    const float* ku_w = (const float*)d_in[12];
    const float* ku_b = (const float*)d_in[13];
    const float* vu_w = (const float*)d_in[14];
    const float* vu_b = (const float*)d_in[15];
    const float* ow = (const float*)d_in[16];
    const float* ob = (const float*)d_in[17];
    const float* ln_g = (const float*)d_in[18];
    const float* ln_b = (const float*)d_in[19];
    const float* fc_w = (const float*)d_in[20];
    const float* fc_b = (const float*)d_in[21];
    float* out = (float*)d_out;

    const int N = in_sizes[0] / 11;
    const int E = in_sizes[1] / 2;
    const int G = out_size / 19;
    const int* esrc = edge_index;
    const int* edst = edge_index + E;

    // workspace carve
    char* ws = (char*)d_ws;
    auto carve = [&](size_t bytes) {
        void* p = (void*)ws;
        ws += WS_ALIGN(bytes);
        return p;
    };
    size_t big = (size_t)N * 128 * sizeof(float);
    float* hA = (float*)carve(big);     // h0 -> q -> (free)
    float* hB = (float*)carve(big);     // hl -> k -> attn_out
    float* hC = (float*)carve(big);     // post-GCN h (residual), kept
    float* hD = (float*)carve(big);     // v
    float* agg = (float*)carve(big);    // attention aggregate
    float* tmp32 = (float*)carve((size_t)N * 32 * sizeof(float));
    float* dinv = (float*)carve((size_t)N * sizeof(float));
    int* cnt = (int*)carve((size_t)N * sizeof(int));
    int* fillcnt = (int*)carve((size_t)N * sizeof(int));
    int* rowptr = (int*)carve((size_t)(N + 1) * sizeof(int));
    int* csr_src = (int*)carve((size_t)E * sizeof(int));
    float* pooled = (float*)carve((size_t)G * 128 * sizeof(float));

    // zero what we accumulate into
    hipMemsetAsync(cnt, 0, (size_t)N * sizeof(int), stream);
    hipMemsetAsync(fillcnt, 0, (size_t)N * sizeof(int), stream);
    hipMemsetAsync(pooled, 0, (size_t)G * 128 * sizeof(float), stream);

    // 1. embedding
    embed_kernel<<<(N * 128 + 255) / 256, 256, 0, stream>>>(x, node_emb, hA, N);

    // 2. GCN linear: hB = hA @ gcn_w
    gemm_rm<128, 128, 8><<<(N + 15) / 16, 256, 0, stream>>>(hA, gcn_w, nullptr, hB, N, 0);

    // 3. degree + CSR
    count_kernel<<<(E + 255) / 256, 256, 0, stream>>>(edst, cnt, E);
    dinv_kernel<<<(N + 255) / 256, 256, 0, stream>>>(cnt, dinv, N);
    scan_kernel<<<1, 1024, 0, stream>>>(cnt, rowptr, N);
    fill_kernel<<<(E + 255) / 256, 256, 0, stream>>>(esrc, edst, rowptr, fillcnt, csr_src, E);

    // 4. GCN aggregate + bias + relu -> hC (residual)
    gcn_agg_kernel<<<(N + 3) / 4, 256, 0, stream>>>(hB, dinv, rowptr, csr_src, gcn_b, hC, N);

    // 5. MLA projections
    gemm_rm<128, 32, 4><<<(N + 31) / 32, 256, 0, stream>>>(hC, qd_w, qd_b, tmp32, N, 0);
    gemm_rm<32, 128, 8><<<(N + 15) / 16, 256, 0, stream>>>(tmp32, qu_w, qu_b, hA, N, 0); // q
    gemm_rm<128, 32, 4><<<(N + 31) / 32, 256, 0, stream>>>(hC, kvd_w, kvd_b, tmp32, N, 0); // ckv
    gemm_rm<32, 128, 8><<<(N + 15) / 16, 256, 0, stream>>>(tmp32, ku_w, ku_b, hB, N, 0); // k
    gemm_rm<32, 128, 8><<<(N + 15) / 16, 256, 0, stream>>>(tmp32, vu_w, vu_b, hD, N, 0); // v

    // 6. attention (online softmax per dst node)
    attn_kernel<<<(N + 3) / 4, 256, 0, stream>>>(hA, hB, hD, rowptr, csr_src, agg, N);

    // 7. output projection: hB = agg @ ow + ob
    gemm_rm<128, 128, 8><<<(N + 15) / 16, 256, 0, stream>>>(agg, ow, ob, hB, N, 0);

    // 8. LN + relu + residual + pool
    ln_pool_kernel<<<(N + 3) / 4, 256, 0, stream>>>(hB, hC, ln_g, ln_b, batch, pooled, N);

    // 9. FC
    fc_kernel<<<(G * 19 + 255) / 256, 256, 0, stream>>>(pooled, fc_w, fc_b, out, G);
}

// Round 5
// 470.652 us; speedup vs baseline: 1.9489x; 1.9489x over previous
//
#include <hip/hip_runtime.h>
#include <hip/hip_bf16.h>

#define WS_ALIGN(x) (((x) + 255) & ~(size_t)255)

// ---------- bf16 helpers ----------
__device__ inline unsigned short f2bf(float f) {
    unsigned int u = __float_as_uint(f);
    u = (u + 0x7fffu + ((u >> 16) & 1u)) >> 16;   // RNE
    return (unsigned short)u;
}
__device__ inline float2 bf2_to_f2(unsigned int u) {
    float lo = __uint_as_float((u & 0xffffu) << 16);
    float hi = __uint_as_float(u & 0xffff0000u);
    return make_float2(lo, hi);
}

// =====================================================================
// GEMM: out[n,128] = A[n,K] @ W[K,128] (+bias). A staged in LDS transposed
// with XOR swizzle (conflict-free writes, broadcast b128 reads).
// Optional embedding indirection for A rows; optional bf16 output.
// Block 256 = 32 col-threads x 8 row-threads; thread tile 8 rows x 4 cols.
// =====================================================================
template <int K, bool BF16OUT>
__global__ __launch_bounds__(256) void gemm_n128(const float* __restrict__ A, const int* __restrict__ xidx,
                                                 const float* __restrict__ emb, const float* __restrict__ W,
                                                 const float* __restrict__ bias, void* __restrict__ outp, int n) {
    __shared__ float As[64 * K];
    const int tid = threadIdx.x;
    const int row0 = blockIdx.x * 64;
    // ---- stage A tile (transposed, swizzled) ----
    constexpr int CH = (64 * K) / (4 * 256);
#pragma unroll
    for (int i = 0; i < CH; ++i) {
        int chunk = tid + i * 256;
        int r = chunk & 63;
        int c4 = chunk >> 6;
        int row = row0 + r;
        float4 v = make_float4(0.f, 0.f, 0.f, 0.f);
        if (row < n) {
            const float* src = xidx ? (emb + ((size_t)xidx[row * 11] << 7) + c4 * 4)
                                    : (A + (size_t)row * K + c4 * 4);
            v = *(const float4*)src;
        }
#pragma unroll
        for (int j = 0; j < 4; ++j) {
            int k = c4 * 4 + j;
            As[k * 64 + (r ^ ((k & 7) << 3))] = (&v.x)[j];
        }
    }
    __syncthreads();
    const int ct = tid & 31, rt = tid >> 5;
    const int c0 = ct * 4, r0 = rt * 8;
    float acc[8][4] = {};
#pragma unroll 4
    for (int k = 0; k < K; ++k) {
        int swz = (k & 7) << 3;
        float4 a0 = *(const float4*)&As[k * 64 + (r0 ^ swz)];
        float4 a1 = *(const float4*)&As[k * 64 + ((r0 + 4) ^ swz)];
        float4 w = *(const float4*)&W[k * 128 + c0];
        float a[8] = {a0.x, a0.y, a0.z, a0.w, a1.x, a1.y, a1.z, a1.w};
#pragma unroll
        for (int i = 0; i < 8; ++i) {
            acc[i][0] = fmaf(a[i], w.x, acc[i][0]);
            acc[i][1] = fmaf(a[i], w.y, acc[i][1]);
            acc[i][2] = fmaf(a[i], w.z, acc[i][2]);
            acc[i][3] = fmaf(a[i], w.w, acc[i][3]);
        }
    }
    float4 bv = make_float4(0.f, 0.f, 0.f, 0.f);
    if (bias) bv = *(const float4*)&bias[c0];
#pragma unroll
    for (int i = 0; i < 8; ++i) {
        int row = row0 + r0 + i;
        if (row < n) {
            float4 o = make_float4(acc[i][0] + bv.x, acc[i][1] + bv.y, acc[i][2] + bv.z, acc[i][3] + bv.w);
            if (BF16OUT) {
                ushort4 u = make_ushort4(f2bf(o.x), f2bf(o.y), f2bf(o.z), f2bf(o.w));
                *(ushort4*)((unsigned short*)outp + (size_t)row * 128 + c0) = u;
            } else {
                *(float4*)((float*)outp + (size_t)row * 128 + c0) = o;
            }
        }
    }
}

// =====================================================================
// Fused qd|kvd: out_q[n,32], out_kv[n,32] = A[n,128] @ {Wq,Wkv}[128,32]
// Block 256 = 16 col-threads (64 cols total) x 16 row-threads; tile 4x4.
// =====================================================================
__global__ __launch_bounds__(256) void gemm_qdkvd(const float* __restrict__ A, const float* __restrict__ Wq,
                                                  const float* __restrict__ Wkv, const float* __restrict__ bq,
                                                  const float* __restrict__ bkv, float* __restrict__ oq,
                                                  float* __restrict__ okv, int n) {
    __shared__ float As[64 * 128];
    const int tid = threadIdx.x;
    const int row0 = blockIdx.x * 64;
#pragma unroll
    for (int i = 0; i < 8; ++i) {
        int chunk = tid + i * 256;
        int r = chunk & 63;
        int c4 = chunk >> 6;
        int row = row0 + r;
        float4 v = make_float4(0.f, 0.f, 0.f, 0.f);
        if (row < n) v = *(const float4*)(A + (size_t)row * 128 + c4 * 4);
#pragma unroll
        for (int j = 0; j < 4; ++j) {
            int k = c4 * 4 + j;
            As[k * 64 + (r ^ ((k & 7) << 3))] = (&v.x)[j];
        }
    }
    __syncthreads();
    const int ct = tid & 15, rt = tid >> 4;
    const int c0 = ct * 4, r0 = rt * 4;
    const float* Wp = (c0 < 32) ? (Wq + c0) : (Wkv + c0 - 32);
    float acc[4][4] = {};
#pragma unroll 4
    for (int k = 0; k < 128; ++k) {
        int swz = (k & 7) << 3;
        float4 a = *(const float4*)&As[k * 64 + (r0 ^ swz)];
        float4 w = *(const float4*)&Wp[k * 32];
        float av[4] = {a.x, a.y, a.z, a.w};
#pragma unroll
        for (int i = 0; i < 4; ++i) {
            acc[i][0] = fmaf(av[i], w.x, acc[i][0]);
            acc[i][1] = fmaf(av[i], w.y, acc[i][1]);
            acc[i][2] = fmaf(av[i], w.z, acc[i][2]);
            acc[i][3] = fmaf(av[i], w.w, acc[i][3]);
        }
    }
    const float* bp = (c0 < 32) ? (bq + c0) : (bkv + c0 - 32);
    float4 bv = *(const float4*)bp;
    float* op = (c0 < 32) ? (oq + c0) : (okv + c0 - 32);
#pragma unroll
    for (int i = 0; i < 4; ++i) {
        int row = row0 + r0 + i;
        if (row < n)
            *(float4*)(op + (size_t)row * 32) =
                make_float4(acc[i][0] + bv.x, acc[i][1] + bv.y, acc[i][2] + bv.z, acc[i][3] + bv.w);
    }
}

// =====================================================================
// Fused ku|vu: k_bf[n,128], v_bf[n,128] = A[n,32] @ {Wk,Wv}[32,128] -> bf16
// Block 256 = 64 col-threads (256 cols total) x 4 row-threads; tile 8x4.
// =====================================================================
__global__ __launch_bounds__(256) void gemm_kuvu(const float* __restrict__ A, const float* __restrict__ Wk,
                                                 const float* __restrict__ Wv, const float* __restrict__ bk,
                                                 const float* __restrict__ bv_, unsigned short* __restrict__ kout,
                                                 unsigned short* __restrict__ vout, int n) {
    __shared__ float As[32 * 32];
    const int tid = threadIdx.x;
    const int row0 = blockIdx.x * 32;
    {
        int r = tid & 31;
        int c4 = tid >> 5;
        int row = row0 + r;
        float4 v = make_float4(0.f, 0.f, 0.f, 0.f);
        if (row < n) v = *(const float4*)(A + (size_t)row * 32 + c4 * 4);
#pragma unroll
        for (int j = 0; j < 4; ++j) {
            int k = c4 * 4 + j;
            As[k * 32 + (r ^ ((k & 3) << 3))] = (&v.x)[j];
        }
    }
    __syncthreads();
    const int ct = tid & 63, rt = tid >> 6;
    const int c0 = ct * 4, r0 = rt * 8;
    const float* Wp = (c0 < 128) ? (Wk + c0) : (Wv + c0 - 128);
    float acc[8][4] = {};
#pragma unroll 4
    for (int k = 0; k < 32; ++k) {
        int swz = (k & 3) << 3;
        float4 a0 = *(const float4*)&As[k * 32 + (r0 ^ swz)];
        float4 a1 = *(const float4*)&As[k * 32 + ((r0 + 4) ^ swz)];
        float4 w = *(const float4*)&Wp[k * 128];
        float a[8] = {a0.x, a0.y, a0.z, a0.w, a1.x, a1.y, a1.z, a1.w};
#pragma unroll
        for (int i = 0; i < 8; ++i) {
            acc[i][0] = fmaf(a[i], w.x, acc[i][0]);
            acc[i][1] = fmaf(a[i], w.y, acc[i][1]);
            acc[i][2] = fmaf(a[i], w.z, acc[i][2]);
            acc[i][3] = fmaf(a[i], w.w, acc[i][3]);
        }
    }
    const float* bp = (c0 < 128) ? (bk + c0) : (bv_ + c0 - 128);
    float4 bvec = *(const float4*)bp;
    unsigned short* op = (c0 < 128) ? (kout + c0) : (vout + c0 - 128);
#pragma unroll
    for (int i = 0; i < 8; ++i) {
        int row = row0 + r0 + i;
        if (row < n) {
            ushort4 u = make_ushort4(f2bf(acc[i][0] + bvec.x), f2bf(acc[i][1] + bvec.y),
                                     f2bf(acc[i][2] + bvec.z), f2bf(acc[i][3] + bvec.w));
            *(ushort4*)(op + (size_t)row * 128) = u;
        }
    }
}

// ---------------- in-degree count ----------------
__global__ void count_kernel(const int* __restrict__ dst, int* __restrict__ cnt, int e) {
    int t = blockIdx.x * blockDim.x + threadIdx.x;
    if (t < e) atomicAdd(&cnt[dst[t]], 1);
}

// ---------------- dinv = rsqrt(in_deg + 1) ----------------
__global__ void dinv_kernel(const int* __restrict__ cnt, float* __restrict__ dinv, int n) {
    int t = blockIdx.x * blockDim.x + threadIdx.x;
    if (t < n) dinv[t] = rsqrtf((float)cnt[t] + 1.0f);
}

// ---------------- parallel scan: partial per-block (1024 elems) ----------------
__global__ __launch_bounds__(256) void scan_partial(const int* __restrict__ cnt, int* __restrict__ rowptr,
                                                    int* __restrict__ bsum, int n) {
    __shared__ int wsum[4];
    int tid = threadIdx.x, lane = tid & 63, wid = tid >> 6;
    int i0 = blockIdx.x * 1024 + tid * 4;
    int e0 = 0, e1 = 0, e2 = 0, e3 = 0;
    if (i0 + 3 < n) {
        int4 v4 = *(const int4*)(cnt + i0);
        e0 = v4.x; e1 = v4.y; e2 = v4.z; e3 = v4.w;
    } else {
        if (i0 < n) e0 = cnt[i0];
        if (i0 + 1 < n) e1 = cnt[i0 + 1];
        if (i0 + 2 < n) e2 = cnt[i0 + 2];
    }
    int s = e0 + e1 + e2 + e3;
    int sc = s;
#pragma unroll
    for (int o = 1; o < 64; o <<= 1) {
        int t = __shfl_up(sc, o);
        if (lane >= o) sc += t;
    }
    if (lane == 63) wsum[wid] = sc;
    __syncthreads();
    int woff = 0;
#pragma unroll
    for (int w = 0; w < 4; ++w)
        if (w < wid) woff += wsum[w];
    int ex = woff + sc - s;
    if (i0 < n) rowptr[i0] = ex;
    if (i0 + 1 < n) rowptr[i0 + 1] = ex + e0;
    if (i0 + 2 < n) rowptr[i0 + 2] = ex + e0 + e1;
    if (i0 + 3 < n) rowptr[i0 + 3] = ex + e0 + e1 + e2;
    if (tid == 255) bsum[blockIdx.x] = woff + sc;
}

// ---------------- scan block sums (assumes nb <= 256) ----------------
__global__ __launch_bounds__(256) void scan_sums(int* __restrict__ bsum, int* __restrict__ rowptr, int nb, int n) {
    __shared__ int wsum[4];
    int tid = threadIdx.x, lane = tid & 63, wid = tid >> 6;
    int v = (tid < nb) ? bsum[tid] : 0;
    int sc = v;
#pragma unroll
    for (int o = 1; o < 64; o <<= 1) {
        int t = __shfl_up(sc, o);
        if (lane >= o) sc += t;
    }
    if (lane == 63) wsum[wid] = sc;
    __syncthreads();
    int woff = 0;
#pragma unroll
    for (int w = 0; w < 4; ++w)
        if (w < wid) woff += wsum[w];
    if (tid < nb) bsum[tid] = woff + sc - v;
    if (tid == 255) rowptr[n] = woff + sc;
}

__global__ void scan_add(int* __restrict__ rowptr, const int* __restrict__ bsum, int n) {
    int i = blockIdx.x * 256 + threadIdx.x;
    if (i < n) rowptr[i] += bsum[i >> 10];
}

// ---------------- CSR fill ----------------
__global__ void fill_kernel(const int* __restrict__ src, const int* __restrict__ dst,
                            const int* __restrict__ rowptr, int* __restrict__ fillcnt,
                            int* __restrict__ csr_src, int e) {
    int t = blockIdx.x * blockDim.x + threadIdx.x;
    if (t >= e) return;
    int d = dst[t];
    int pos = rowptr[d] + atomicAdd(&fillcnt[d], 1);
    csr_src[pos] = src[t];
}

// ---------------- GCN aggregate (bf16 hl gather) ----------------
__global__ __launch_bounds__(256) void gcn_agg_kernel(const unsigned short* __restrict__ hl, const float* __restrict__ dinv,
                                                      const int* __restrict__ rowptr, const int* __restrict__ csr_src,
                                                      const float* __restrict__ bias, float* __restrict__ out, int n) {
    int wave = threadIdx.x >> 6, lane = threadIdx.x & 63;
    int node = blockIdx.x * 4 + wave;
    if (node >= n) return;
    float dn = dinv[node];
    float2 sv = bf2_to_f2(((const unsigned int*)(hl + (size_t)node * 128))[lane]);
    float a0 = sv.x * dn * dn, a1 = sv.y * dn * dn;
    int beg = rowptr[node], end = rowptr[node + 1];
    int idx = beg;
    for (; idx + 2 <= end; idx += 2) {
        int s0 = csr_src[idx], s1 = csr_src[idx + 1];
        unsigned int u0 = ((const unsigned int*)(hl + (size_t)s0 * 128))[lane];
        unsigned int u1 = ((const unsigned int*)(hl + (size_t)s1 * 128))[lane];
        float w0 = dinv[s0] * dn, w1 = dinv[s1] * dn;
        float2 h0 = bf2_to_f2(u0), h1 = bf2_to_f2(u1);
        a0 += h0.x * w0 + h1.x * w1;
        a1 += h0.y * w0 + h1.y * w1;
    }
    if (idx < end) {
        int s = csr_src[idx];
        float w = dinv[s] * dn;
        float2 h = bf2_to_f2(((const unsigned int*)(hl + (size_t)s * 128))[lane]);
        a0 += h.x * w;
        a1 += h.y * w;
    }
    int d0 = lane * 2;
    a0 = fmaxf(a0 + bias[d0], 0.f);
    a1 = fmaxf(a1 + bias[d0 + 1], 0.f);
    ((float2*)(out + (size_t)node * 128))[lane] = make_float2(a0, a1);
}

// ---------------- MLA attention (bf16 k/v gather, online softmax) ----------------
__global__ __launch_bounds__(256) void attn_kernel(const float* __restrict__ q, const unsigned short* __restrict__ kbf,
                                                   const unsigned short* __restrict__ vbf, const int* __restrict__ rowptr,
                                                   const int* __restrict__ csr_src, float* __restrict__ agg, int n) {
    int wave = threadIdx.x >> 6, lane = threadIdx.x & 63;
    int node = blockIdx.x * 4 + wave;
    if (node >= n) return;
    float2 qv = ((const float2*)(q + (size_t)node * 128))[lane];
    int beg = rowptr[node], end = rowptr[node + 1];
    float m = -INFINITY, den = 0.f, a0 = 0.f, a1 = 0.f;
    int idx = beg;
    for (; idx + 2 <= end; idx += 2) {
        int s0 = csr_src[idx], s1 = csr_src[idx + 1];
        unsigned int ku0 = ((const unsigned int*)(kbf + (size_t)s0 * 128))[lane];
        unsigned int ku1 = ((const unsigned int*)(kbf + (size_t)s1 * 128))[lane];
        unsigned int vu0 = ((const unsigned int*)(vbf + (size_t)s0 * 128))[lane];
        unsigned int vu1 = ((const unsigned int*)(vbf + (size_t)s1 * 128))[lane];
        float2 k0 = bf2_to_f2(ku0), k1 = bf2_to_f2(ku1);
        float p0 = qv.x * k0.x + qv.y * k0.y;
        float p1 = qv.x * k1.x + qv.y * k1.y;
        p0 += __shfl_xor(p0, 1); p1 += __shfl_xor(p1, 1);
        p0 += __shfl_xor(p0, 2); p1 += __shfl_xor(p1, 2);
        p0 += __shfl_xor(p0, 4); p1 += __shfl_xor(p1, 4);
        float s0s = p0 * 0.25f, s1s = p1 * 0.25f;
        float mnew = fmaxf(m, fmaxf(s0s, s1s));
        float corr = __expf(m - mnew);
        float e0 = __expf(s0s - mnew), e1 = __expf(s1s - mnew);
        den = den * corr + e0 + e1;
        float2 v0 = bf2_to_f2(vu0), v1 = bf2_to_f2(vu1);
        a0 = a0 * corr + e0 * v0.x + e1 * v1.x;
        a1 = a1 * corr + e0 * v0.y + e1 * v1.y;
        m = mnew;
    }
    if (idx < end) {
        int s = csr_src[idx];
        unsigned int ku = ((const unsigned int*)(kbf + (size_t)s * 128))[lane];
        unsigned int vu = ((const unsigned int*)(vbf + (size_t)s * 128))[lane];
        float2 kv = bf2_to_f2(ku);
        float p = qv.x * kv.x + qv.y * kv.y;
        p += __shfl_xor(p, 1);
        p += __shfl_xor(p, 2);
        p += __shfl_xor(p, 4);
        float sc = p * 0.25f;
        float mnew = fmaxf(m, sc);
        float corr = __expf(m - mnew);
        float e0 = __expf(sc - mnew);
        den = den * corr + e0;
        float2 vv = bf2_to_f2(vu);
        a0 = a0 * corr + e0 * vv.x;
        a1 = a1 * corr + e0 * vv.y;
    }
    float r = (end > beg) ? 1.f / fmaxf(den, 1e-16f) : 0.f;
    ((float2*)(agg + (size_t)node * 128))[lane] = make_float2(a0 * r, a1 * r);
}

// ---------------- LN(x+res)*g+b, relu, in place on h ----------------
__global__ __launch_bounds__(256) void ln_kernel(float* __restrict__ h, const float* __restrict__ res,
                                                 const float* __restrict__ g, const float* __restrict__ b, int n) {
    int wave = threadIdx.x >> 6, lane = threadIdx.x & 63;
    int node = blockIdx.x * 4 + wave;
    if (node >= n) return;
    float2 x = ((const float2*)(h + (size_t)node * 128))[lane];
    float2 rr = ((const float2*)(res + (size_t)node * 128))[lane];
    x.x += rr.x;
    x.y += rr.y;
    float s = x.x + x.y;
#pragma unroll
    for (int o = 1; o < 64; o <<= 1) s += __shfl_xor(s, o);
    float mu = s * (1.f / 128.f);
    float dx = x.x - mu, dy = x.y - mu;
    float vs = dx * dx + dy * dy;
#pragma unroll
    for (int o = 1; o < 64; o <<= 1) vs += __shfl_xor(vs, o);
    float rstd = rsqrtf(vs * (1.f / 128.f) + 1e-5f);
    int d0 = lane * 2;
    float y0 = fmaxf(dx * rstd * g[d0] + b[d0], 0.f);
    float y1 = fmaxf(dy * rstd * g[d0 + 1] + b[d0 + 1], 0.f);
    ((float2*)(h + (size_t)node * 128))[lane] = make_float2(y0, y1);
}

// ---------------- segment bounds from sorted batch: gstart[0..G] ----------------
__global__ void seg_bounds(const int* __restrict__ batch, int* __restrict__ gstart, int n, int G) {
    int i = blockIdx.x * 256 + threadIdx.x;
    if (i >= n) return;
    int bcur = batch[i];
    int bprev = (i == 0) ? -1 : batch[i - 1];
    for (int g = bprev + 1; g <= bcur; ++g) gstart[g] = i;
    if (i == n - 1)
        for (int g = bcur + 1; g <= G; ++g) gstart[g] = n;
}

// ---------------- pool: one wave per graph, contiguous node range ----------------
__global__ __launch_bounds__(256) void pool_kernel(const float* __restrict__ hF, const int* __restrict__ gstart,
                                                   float* __restrict__ pooled, int G) {
    int wave = threadIdx.x >> 6, lane = threadIdx.x & 63;
    int g = blockIdx.x * 4 + wave;
    if (g >= G) return;
    int s = gstart[g], e = gstart[g + 1];
    float a0 = 0.f, a1 = 0.f;
    for (int i = s; i < e; ++i) {
        float2 v = ((const float2*)(hF + (size_t)i * 128))[lane];
        a0 += v.x;
        a1 += v.y;
    }
    ((float2*)(pooled + (size_t)g * 128))[lane] = make_float2(a0, a1);
}

// ---------------- final FC ----------------
__global__ void fc_kernel(const float* __restrict__ pooled, const float* __restrict__ w,
                          const float* __restrict__ bias, float* __restrict__ out, int gcount) {
    int idx = blockIdx.x * blockDim.x + threadIdx.x;
    if (idx >= gcount * 19) return;
    int gi = idx / 19, j = idx % 19;
    float acc = bias[j];
#pragma unroll 8
    for (int k = 0; k < 128; ++k) acc += pooled[(size_t)gi * 128 + k] * w[k * 19 + j];
    out[idx] = acc;
}

extern "C" void kernel_launch(void* const* d_in, const int* in_sizes, int n_in,
                              void* d_out, int out_size, void* d_ws, size_t ws_size,
                              hipStream_t stream) {
    const int* x = (const int*)d_in[0];
    const int* edge_index = (const int*)d_in[1];
    const int* batch = (const int*)d_in[2];
    const float* node_emb = (const float*)d_in[3];
    const float* gcn_w = (const float*)d_in[4];
    const float* gcn_b = (const float*)d_in[5];
    const float* qd_w = (const float*)d_in[6];
    const float* qd_b = (const float*)d_in[7];
    const float* qu_w = (const float*)d_in[8];
    const float* qu_b = (const float*)d_in[9];
    const float* kvd_w = (const float*)d_in[10];
    const float* kvd_b = (const float*)d_in[11];
    const float* ku_w = (const float*)d_in[12];
    const float* ku_b = (const float*)d_in[13];
    const float* vu_w = (const float*)d_in[14];
    const float* vu_b = (const float*)d_in[15];
    const float* ow = (const float*)d_in[16];
    const float* ob = (const float*)d_in[17];
    const float* ln_g = (const float*)d_in[18];
    const float* ln_b = (const float*)d_in[19];
    const float* fc_w = (const float*)d_in[20];
    const float* fc_b = (const float*)d_in[21];
    float* out = (float*)d_out;

    const int N = in_sizes[0] / 11;
    const int E = in_sizes[1] / 2;
    const int G = out_size / 19;
    const int* esrc = edge_index;
    const int* edst = edge_index + E;

    char* ws = (char*)d_ws;
    auto carve = [&](size_t bytes) {
        void* p = (void*)ws;
        ws += WS_ALIGN(bytes);
        return p;
    };
    unsigned short* hB_bf = (unsigned short*)carve((size_t)N * 128 * 2);  // GCN-linear out (bf16)
    float* hC = (float*)carve((size_t)N * 128 * 4);                        // post-GCN residual
    float* q = (float*)carve((size_t)N * 128 * 4);                         // q; reused as hOut
    unsigned short* k_bf = (unsigned short*)carve((size_t)N * 128 * 2);
    unsigned short* v_bf = (unsigned short*)carve((size_t)N * 128 * 2);
    float* agg = (float*)carve((size_t)N * 128 * 4);
    float* q32 = (float*)carve((size_t)N * 32 * 4);
    float* kv32 = (float*)carve((size_t)N * 32 * 4);
    float* dinv = (float*)carve((size_t)N * 4);
    int* cnt = (int*)carve((size_t)N * 4);
    int* fillcnt = (int*)carve((size_t)N * 4);
    int* rowptr = (int*)carve((size_t)(N + 1) * 4);
    int* bsum = (int*)carve(4096);
    int* gstart = (int*)carve((size_t)(G + 1) * 4);
    int* csr_src = (int*)carve((size_t)E * 4);
    float* pooled = (float*)carve((size_t)G * 128 * 4);
    float* hOut = q;  // q dead after attn

    hipMemsetAsync(cnt, 0, (size_t)N * 4, stream);
    hipMemsetAsync(fillcnt, 0, (size_t)N * 4, stream);

    const int nb = (N + 1023) / 1024;

    // 1. GCN linear with fused embedding gather -> hB_bf (bf16)
    gemm_n128<128, true><<<(N + 63) / 64, 256, 0, stream>>>(nullptr, x, node_emb, gcn_w, nullptr, hB_bf, N);

    // 2. degree + CSR
    count_kernel<<<(E + 255) / 256, 256, 0, stream>>>(edst, cnt, E);
    dinv_kernel<<<(N + 255) / 256, 256, 0, stream>>>(cnt, dinv, N);
    scan_partial<<<nb, 256, 0, stream>>>(cnt, rowptr, bsum, N);
    scan_sums<<<1, 256, 0, stream>>>(bsum, rowptr, nb, N);
    scan_add<<<(N + 255) / 256, 256, 0, stream>>>(rowptr, bsum, N);
    fill_kernel<<<(E + 255) / 256, 256, 0, stream>>>(esrc, edst, rowptr, fillcnt, csr_src, E);

    // 3. GCN aggregate + bias + relu -> hC (residual, f32)
    gcn_agg_kernel<<<(N + 3) / 4, 256, 0, stream>>>(hB_bf, dinv, rowptr, csr_src, gcn_b, hC, N);

    // 4. MLA projections
    gemm_qdkvd<<<(N + 63) / 64, 256, 0, stream>>>(hC, qd_w, kvd_w, qd_b, kvd_b, q32, kv32, N);
    gemm_n128<32, false><<<(N + 63) / 64, 256, 0, stream>>>(q32, nullptr, nullptr, qu_w, qu_b, q, N);
    gemm_kuvu<<<(N + 31) / 32, 256, 0, stream>>>(kv32, ku_w, vu_w, ku_b, vu_b, k_bf, v_bf, N);

    // 5. attention
    attn_kernel<<<(N + 3) / 4, 256, 0, stream>>>(q, k_bf, v_bf, rowptr, csr_src, agg, N);

    // 6. output projection -> hOut (aliases q)
    gemm_n128<128, false><<<(N + 63) / 64, 256, 0, stream>>>(agg, nullptr, nullptr, ow, ob, hOut, N);

    // 7. LN + relu (in place on hOut)
    ln_kernel<<<(N + 3) / 4, 256, 0, stream>>>(hOut, hC, ln_g, ln_b, N);

    // 8. pool + FC
    seg_bounds<<<(N + 255) / 256, 256, 0, stream>>>(batch, gstart, N, G);
    pool_kernel<<<(G + 3) / 4, 256, 0, stream>>>(hOut, gstart, pooled, G);
    fc_kernel<<<(G * 19 + 255) / 256, 256, 0, stream>>>(pooled, fc_w, fc_b, out, G);
}

// Round 7
// 448.279 us; speedup vs baseline: 2.0462x; 1.0499x over previous
//
#include <hip/hip_runtime.h>
#include <hip/hip_bf16.h>

#define WS_ALIGN(x) (((x) + 255) & ~(size_t)255)

// ---------- bf16 helpers ----------
__device__ inline unsigned short f2bf(float f) {
    unsigned int u = __float_as_uint(f);
    u = (u + 0x7fffu + ((u >> 16) & 1u)) >> 16;   // RNE
    return (unsigned short)u;
}
__device__ inline float2 bf2_to_f2(unsigned int u) {
    float lo = __uint_as_float((u & 0xffffu) << 16);
    float hi = __uint_as_float(u & 0xffff0000u);
    return make_float2(lo, hi);
}

// =====================================================================
// GEMM: out[n,128] = A[n,K] @ W[K,128] (+bias). A staged in LDS transposed
// with XOR swizzle. MODE: 0 = f32 out, 1 = bf16 out, 2 = f32 + fused
// (residual add + LayerNorm + ReLU) epilogue.
// Block 256 = 32 col-threads x 8 row-threads; thread tile 8 rows x 4 cols.
// Row r0+i is held by the 32 lanes sharing rt -> LN reduce = 5-step shfl_xor.
// =====================================================================
template <int K, int MODE>
__global__ __launch_bounds__(256) void gemm_n128(const float* __restrict__ A, const int* __restrict__ xidx,
                                                 const float* __restrict__ emb, const float* __restrict__ W,
                                                 const float* __restrict__ bias, void* __restrict__ outp,
                                                 const float* __restrict__ res, const float* __restrict__ lng,
                                                 const float* __restrict__ lnb, int n) {
    __shared__ float As[64 * K];
    const int tid = threadIdx.x;
    const int row0 = blockIdx.x * 64;
    constexpr int CH = (64 * K) / (4 * 256);
#pragma unroll
    for (int i = 0; i < CH; ++i) {
        int chunk = tid + i * 256;
        int r = chunk & 63;
        int c4 = chunk >> 6;
        int row = row0 + r;
        float4 v = make_float4(0.f, 0.f, 0.f, 0.f);
        if (row < n) {
            const float* src = xidx ? (emb + ((size_t)xidx[row * 11] << 7) + c4 * 4)
                                    : (A + (size_t)row * K + c4 * 4);
            v = *(const float4*)src;
        }
#pragma unroll
        for (int j = 0; j < 4; ++j) {
            int k = c4 * 4 + j;
            As[k * 64 + (r ^ ((k & 7) << 3))] = (&v.x)[j];
        }
    }
    __syncthreads();
    const int ct = tid & 31, rt = tid >> 5;
    const int c0 = ct * 4, r0 = rt * 8;
    float acc[8][4] = {};
#pragma unroll 4
    for (int k = 0; k < K; ++k) {
        int swz = (k & 7) << 3;
        float4 a0 = *(const float4*)&As[k * 64 + (r0 ^ swz)];
        float4 a1 = *(const float4*)&As[k * 64 + ((r0 + 4) ^ swz)];
        float4 w = *(const float4*)&W[k * 128 + c0];
        float a[8] = {a0.x, a0.y, a0.z, a0.w, a1.x, a1.y, a1.z, a1.w};
#pragma unroll
        for (int i = 0; i < 8; ++i) {
            acc[i][0] = fmaf(a[i], w.x, acc[i][0]);
            acc[i][1] = fmaf(a[i], w.y, acc[i][1]);
            acc[i][2] = fmaf(a[i], w.z, acc[i][2]);
            acc[i][3] = fmaf(a[i], w.w, acc[i][3]);
        }
    }
    float4 bv = make_float4(0.f, 0.f, 0.f, 0.f);
    if (bias) bv = *(const float4*)&bias[c0];
    if constexpr (MODE == 2) {
        float4 gv = *(const float4*)&lng[c0];
        float4 lbv = *(const float4*)&lnb[c0];
#pragma unroll
        for (int i = 0; i < 8; ++i) {
            int row = row0 + r0 + i;
            if (row < n) {
                float4 rr = *(const float4*)(res + (size_t)row * 128 + c0);
                float o0 = acc[i][0] + bv.x + rr.x;
                float o1 = acc[i][1] + bv.y + rr.y;
                float o2 = acc[i][2] + bv.z + rr.z;
                float o3 = acc[i][3] + bv.w + rr.w;
                float s = o0 + o1 + o2 + o3;
#pragma unroll
                for (int o = 1; o < 32; o <<= 1) s += __shfl_xor(s, o);
                float mu = s * (1.f / 128.f);
                float d0 = o0 - mu, d1 = o1 - mu, d2 = o2 - mu, d3 = o3 - mu;
                float vs = d0 * d0 + d1 * d1 + d2 * d2 + d3 * d3;
#pragma unroll
                for (int o = 1; o < 32; o <<= 1) vs += __shfl_xor(vs, o);
                float rstd = rsqrtf(vs * (1.f / 128.f) + 1e-5f);
                float4 y = make_float4(fmaxf(d0 * rstd * gv.x + lbv.x, 0.f),
                                       fmaxf(d1 * rstd * gv.y + lbv.y, 0.f),
                                       fmaxf(d2 * rstd * gv.z + lbv.z, 0.f),
                                       fmaxf(d3 * rstd * gv.w + lbv.w, 0.f));
                *(float4*)((float*)outp + (size_t)row * 128 + c0) = y;
            }
        }
    } else {
#pragma unroll
        for (int i = 0; i < 8; ++i) {
            int row = row0 + r0 + i;
            if (row < n) {
                float4 o = make_float4(acc[i][0] + bv.x, acc[i][1] + bv.y, acc[i][2] + bv.z, acc[i][3] + bv.w);
                if constexpr (MODE == 1) {
                    ushort4 u = make_ushort4(f2bf(o.x), f2bf(o.y), f2bf(o.z), f2bf(o.w));
                    *(ushort4*)((unsigned short*)outp + (size_t)row * 128 + c0) = u;
                } else {
                    *(float4*)((float*)outp + (size_t)row * 128 + c0) = o;
                }
            }
        }
    }
}

// =====================================================================
// Fused qd|kvd: out_q[n,32], out_kv[n,32] = A[n,128] @ {Wq,Wkv}[128,32]
// =====================================================================
__global__ __launch_bounds__(256) void gemm_qdkvd(const float* __restrict__ A, const float* __restrict__ Wq,
                                                  const float* __restrict__ Wkv, const float* __restrict__ bq,
                                                  const float* __restrict__ bkv, float* __restrict__ oq,
                                                  float* __restrict__ okv, int n) {
    __shared__ float As[64 * 128];
    const int tid = threadIdx.x;
    const int row0 = blockIdx.x * 64;
#pragma unroll
    for (int i = 0; i < 8; ++i) {
        int chunk = tid + i * 256;
        int r = chunk & 63;
        int c4 = chunk >> 6;
        int row = row0 + r;
        float4 v = make_float4(0.f, 0.f, 0.f, 0.f);
        if (row < n) v = *(const float4*)(A + (size_t)row * 128 + c4 * 4);
#pragma unroll
        for (int j = 0; j < 4; ++j) {
            int k = c4 * 4 + j;
            As[k * 64 + (r ^ ((k & 7) << 3))] = (&v.x)[j];
        }
    }
    __syncthreads();
    const int ct = tid & 15, rt = tid >> 4;
    const int c0 = ct * 4, r0 = rt * 4;
    const float* Wp = (c0 < 32) ? (Wq + c0) : (Wkv + c0 - 32);
    float acc[4][4] = {};
#pragma unroll 4
    for (int k = 0; k < 128; ++k) {
        int swz = (k & 7) << 3;
        float4 a = *(const float4*)&As[k * 64 + (r0 ^ swz)];
        float4 w = *(const float4*)&Wp[k * 32];
        float av[4] = {a.x, a.y, a.z, a.w};
#pragma unroll
        for (int i = 0; i < 4; ++i) {
            acc[i][0] = fmaf(av[i], w.x, acc[i][0]);
            acc[i][1] = fmaf(av[i], w.y, acc[i][1]);
            acc[i][2] = fmaf(av[i], w.z, acc[i][2]);
            acc[i][3] = fmaf(av[i], w.w, acc[i][3]);
        }
    }
    const float* bp = (c0 < 32) ? (bq + c0) : (bkv + c0 - 32);
    float4 bv = *(const float4*)bp;
    float* op = (c0 < 32) ? (oq + c0) : (okv + c0 - 32);
#pragma unroll
    for (int i = 0; i < 4; ++i) {
        int row = row0 + r0 + i;
        if (row < n)
            *(float4*)(op + (size_t)row * 32) =
                make_float4(acc[i][0] + bv.x, acc[i][1] + bv.y, acc[i][2] + bv.z, acc[i][3] + bv.w);
    }
}

// =====================================================================
// Fused ku|vu -> interleaved kv_bf[n][256] (cols 0-127 = K, 128-255 = V)
// =====================================================================
__global__ __launch_bounds__(256) void gemm_kuvu(const float* __restrict__ A, const float* __restrict__ Wk,
                                                 const float* __restrict__ Wv, const float* __restrict__ bk,
                                                 const float* __restrict__ bv_, unsigned short* __restrict__ kv,
                                                 int n) {
    __shared__ float As[32 * 32];
    const int tid = threadIdx.x;
    const int row0 = blockIdx.x * 32;
    {
        int r = tid & 31;
        int c4 = tid >> 5;
        int row = row0 + r;
        float4 v = make_float4(0.f, 0.f, 0.f, 0.f);
        if (row < n) v = *(const float4*)(A + (size_t)row * 32 + c4 * 4);
#pragma unroll
        for (int j = 0; j < 4; ++j) {
            int k = c4 * 4 + j;
            As[k * 32 + (r ^ ((k & 3) << 3))] = (&v.x)[j];
        }
    }
    __syncthreads();
    const int ct = tid & 63, rt = tid >> 6;
    const int c0 = ct * 4, r0 = rt * 8;
    const float* Wp = (c0 < 128) ? (Wk + c0) : (Wv + c0 - 128);
    float acc[8][4] = {};
#pragma unroll 4
    for (int k = 0; k < 32; ++k) {
        int swz = (k & 3) << 3;
        float4 a0 = *(const float4*)&As[k * 32 + (r0 ^ swz)];
        float4 a1 = *(const float4*)&As[k * 32 + ((r0 + 4) ^ swz)];
        float4 w = *(const float4*)&Wp[k * 128];
        float a[8] = {a0.x, a0.y, a0.z, a0.w, a1.x, a1.y, a1.z, a1.w};
#pragma unroll
        for (int i = 0; i < 8; ++i) {
            acc[i][0] = fmaf(a[i], w.x, acc[i][0]);
            acc[i][1] = fmaf(a[i], w.y, acc[i][1]);
            acc[i][2] = fmaf(a[i], w.z, acc[i][2]);
            acc[i][3] = fmaf(a[i], w.w, acc[i][3]);
        }
    }
    const float* bp = (c0 < 128) ? (bk + c0) : (bv_ + c0 - 128);
    float4 bvec = *(const float4*)bp;
#pragma unroll
    for (int i = 0; i < 8; ++i) {
        int row = row0 + r0 + i;
        if (row < n) {
            ushort4 u = make_ushort4(f2bf(acc[i][0] + bvec.x), f2bf(acc[i][1] + bvec.y),
                                     f2bf(acc[i][2] + bvec.z), f2bf(acc[i][3] + bvec.w));
            *(ushort4*)(kv + (size_t)row * 256 + c0) = u;
        }
    }
}

// ---------------- in-degree count ----------------
__global__ void count_kernel(const int* __restrict__ dst, int* __restrict__ cnt, int e) {
    int t = blockIdx.x * blockDim.x + threadIdx.x;
    if (t < e) atomicAdd(&cnt[dst[t]], 1);
}

// ---------------- parallel scan (1024/block) + fused dinv ----------------
__global__ __launch_bounds__(256) void scan_partial(const int* __restrict__ cnt, int* __restrict__ rowptr,
                                                    int* __restrict__ bsum, float* __restrict__ dinv, int n) {
    __shared__ int wsum[4];
    int tid = threadIdx.x, lane = tid & 63, wid = tid >> 6;
    int i0 = blockIdx.x * 1024 + tid * 4;
    int e0 = 0, e1 = 0, e2 = 0, e3 = 0;
    if (i0 + 3 < n) {
        int4 v4 = *(const int4*)(cnt + i0);
        e0 = v4.x; e1 = v4.y; e2 = v4.z; e3 = v4.w;
    } else {
        if (i0 < n) e0 = cnt[i0];
        if (i0 + 1 < n) e1 = cnt[i0 + 1];
        if (i0 + 2 < n) e2 = cnt[i0 + 2];
    }
    int s = e0 + e1 + e2 + e3;
    int sc = s;
#pragma unroll
    for (int o = 1; o < 64; o <<= 1) {
        int t = __shfl_up(sc, o);
        if (lane >= o) sc += t;
    }
    if (lane == 63) wsum[wid] = sc;
    __syncthreads();
    int woff = 0;
#pragma unroll
    for (int w = 0; w < 4; ++w)
        if (w < wid) woff += wsum[w];
    int ex = woff + sc - s;
    if (i0 < n)     { rowptr[i0] = ex;                dinv[i0] = rsqrtf((float)e0 + 1.f); }
    if (i0 + 1 < n) { rowptr[i0 + 1] = ex + e0;       dinv[i0 + 1] = rsqrtf((float)e1 + 1.f); }
    if (i0 + 2 < n) { rowptr[i0 + 2] = ex + e0 + e1;  dinv[i0 + 2] = rsqrtf((float)e2 + 1.f); }
    if (i0 + 3 < n) { rowptr[i0 + 3] = ex + e0 + e1 + e2; dinv[i0 + 3] = rsqrtf((float)e3 + 1.f); }
    if (tid == 255) bsum[blockIdx.x] = woff + sc;
}

// ---------------- scan block sums (nb <= 256) ----------------
__global__ __launch_bounds__(256) void scan_sums(int* __restrict__ bsum, int* __restrict__ rowptr, int nb, int n) {
    __shared__ int wsum[4];
    int tid = threadIdx.x, lane = tid & 63, wid = tid >> 6;
    int v = (tid < nb) ? bsum[tid] : 0;
    int sc = v;
#pragma unroll
    for (int o = 1; o < 64; o <<= 1) {
        int t = __shfl_up(sc, o);
        if (lane >= o) sc += t;
    }
    if (lane == 63) wsum[wid] = sc;
    __syncthreads();
    int woff = 0;
#pragma unroll
    for (int w = 0; w < 4; ++w)
        if (w < wid) woff += wsum[w];
    if (tid < nb) bsum[tid] = woff + sc - v;
    if (tid == 255) rowptr[n] = woff + sc;
}

__global__ void scan_add(int* __restrict__ rowptr, const int* __restrict__ bsum, int n) {
    int i = blockIdx.x * 256 + threadIdx.x;
    if (i < n) rowptr[i] += bsum[i >> 10];
}

// ---------------- CSR fill ----------------
__global__ void fill_kernel(const int* __restrict__ src, const int* __restrict__ dst,
                            const int* __restrict__ rowptr, int* __restrict__ fillcnt,
                            int* __restrict__ csr_src, int e) {
    int t = blockIdx.x * blockDim.x + threadIdx.x;
    if (t >= e) return;
    int d = dst[t];
    int pos = rowptr[d] + atomicAdd(&fillcnt[d], 1);
    csr_src[pos] = src[t];
}

// ---------------- GCN aggregate (bf16 gather, 4-unrolled) ----------------
__global__ __launch_bounds__(256) void gcn_agg_kernel(const unsigned short* __restrict__ hl, const float* __restrict__ dinv,
                                                      const int* __restrict__ rowptr, const int* __restrict__ csr_src,
                                                      const float* __restrict__ bias, float* __restrict__ out, int n) {
    int wave = threadIdx.x >> 6, lane = threadIdx.x & 63;
    int node = blockIdx.x * 4 + wave;
    if (node >= n) return;
    float dn = dinv[node];
    float2 sv = bf2_to_f2(((const unsigned int*)(hl + (size_t)node * 128))[lane]);
    float a0 = sv.x * dn * dn, a1 = sv.y * dn * dn;
    int beg = rowptr[node], end = rowptr[node + 1];
    int idx = beg;
    for (; idx + 4 <= end; idx += 4) {
        int s0 = csr_src[idx], s1 = csr_src[idx + 1], s2 = csr_src[idx + 2], s3 = csr_src[idx + 3];
        unsigned int u0 = ((const unsigned int*)(hl + (size_t)s0 * 128))[lane];
        unsigned int u1 = ((const unsigned int*)(hl + (size_t)s1 * 128))[lane];
        unsigned int u2 = ((const unsigned int*)(hl + (size_t)s2 * 128))[lane];
        unsigned int u3 = ((const unsigned int*)(hl + (size_t)s3 * 128))[lane];
        float w0 = dinv[s0] * dn, w1 = dinv[s1] * dn, w2 = dinv[s2] * dn, w3 = dinv[s3] * dn;
        float2 h0 = bf2_to_f2(u0), h1 = bf2_to_f2(u1), h2 = bf2_to_f2(u2), h3 = bf2_to_f2(u3);
        a0 += h0.x * w0 + h1.x * w1 + h2.x * w2 + h3.x * w3;
        a1 += h0.y * w0 + h1.y * w1 + h2.y * w2 + h3.y * w3;
    }
    for (; idx < end; ++idx) {
        int s = csr_src[idx];
        float w = dinv[s] * dn;
        float2 h = bf2_to_f2(((const unsigned int*)(hl + (size_t)s * 128))[lane]);
        a0 += h.x * w;
        a1 += h.y * w;
    }
    int d0 = lane * 2;
    a0 = fmaxf(a0 + bias[d0], 0.f);
    a1 = fmaxf(a1 + bias[d0 + 1], 0.f);
    ((float2*)(out + (size_t)node * 128))[lane] = make_float2(a0, a1);
}

// ---------------- MLA attention (interleaved bf16 kv, 4-unrolled) ----------------
__global__ __launch_bounds__(256) void attn_kernel(const float* __restrict__ q, const unsigned short* __restrict__ kv,
                                                   const int* __restrict__ rowptr, const int* __restrict__ csr_src,
                                                   float* __restrict__ agg, int n) {
    int wave = threadIdx.x >> 6, lane = threadIdx.x & 63;
    int node = blockIdx.x * 4 + wave;
    if (node >= n) return;
    float2 qv = ((const float2*)(q + (size_t)node * 128))[lane];
    int beg = rowptr[node], end = rowptr[node + 1];
    float m = -INFINITY, den = 0.f, a0 = 0.f, a1 = 0.f;
    int idx = beg;
    for (; idx + 4 <= end; idx += 4) {
        int s0 = csr_src[idx], s1 = csr_src[idx + 1], s2 = csr_src[idx + 2], s3 = csr_src[idx + 3];
        const unsigned int* r0 = (const unsigned int*)(kv + (size_t)s0 * 256);
        const unsigned int* r1 = (const unsigned int*)(kv + (size_t)s1 * 256);
        const unsigned int* r2 = (const unsigned int*)(kv + (size_t)s2 * 256);
        const unsigned int* r3 = (const unsigned int*)(kv + (size_t)s3 * 256);
        unsigned int ku0 = r0[lane], vu0 = r0[64 + lane];
        unsigned int ku1 = r1[lane], vu1 = r1[64 + lane];
        unsigned int ku2 = r2[lane], vu2 = r2[64 + lane];
        unsigned int ku3 = r3[lane], vu3 = r3[64 + lane];
        float2 k0 = bf2_to_f2(ku0), k1 = bf2_to_f2(ku1), k2 = bf2_to_f2(ku2), k3 = bf2_to_f2(ku3);
        float p0 = qv.x * k0.x + qv.y * k0.y;
        float p1 = qv.x * k1.x + qv.y * k1.y;
        float p2 = qv.x * k2.x + qv.y * k2.y;
        float p3 = qv.x * k3.x + qv.y * k3.y;
        p0 += __shfl_xor(p0, 1); p1 += __shfl_xor(p1, 1); p2 += __shfl_xor(p2, 1); p3 += __shfl_xor(p3, 1);
        p0 += __shfl_xor(p0, 2); p1 += __shfl_xor(p1, 2); p2 += __shfl_xor(p2, 2); p3 += __shfl_xor(p3, 2);
        p0 += __shfl_xor(p0, 4); p1 += __shfl_xor(p1, 4); p2 += __shfl_xor(p2, 4); p3 += __shfl_xor(p3, 4);
        float sc0 = p0 * 0.25f, sc1 = p1 * 0.25f, sc2 = p2 * 0.25f, sc3 = p3 * 0.25f;
        float smax = fmaxf(fmaxf(sc0, sc1), fmaxf(sc2, sc3));
        float mnew = fmaxf(m, smax);
        float corr = __expf(m - mnew);   // exp(-inf)=0 first time
        float e0 = __expf(sc0 - mnew), e1 = __expf(sc1 - mnew);
        float e2 = __expf(sc2 - mnew), e3 = __expf(sc3 - mnew);
        den = den * corr + (e0 + e1) + (e2 + e3);
        float2 v0 = bf2_to_f2(vu0), v1 = bf2_to_f2(vu1), v2 = bf2_to_f2(vu2), v3 = bf2_to_f2(vu3);
        a0 = a0 * corr + e0 * v0.x + e1 * v1.x + e2 * v2.x + e3 * v3.x;
        a1 = a1 * corr + e0 * v0.y + e1 * v1.y + e2 * v2.y + e3 * v3.y;
        m = mnew;
    }
    for (; idx < end; ++idx) {
        int s = csr_src[idx];
        const unsigned int* r = (const unsigned int*)(kv + (size_t)s * 256);
        unsigned int ku = r[lane], vu = r[64 + lane];
        float2 kvv = bf2_to_f2(ku);
        float p = qv.x * kvv.x + qv.y * kvv.y;
        p += __shfl_xor(p, 1);
        p += __shfl_xor(p, 2);
        p += __shfl_xor(p, 4);
        float sc = p * 0.25f;
        float mnew = fmaxf(m, sc);
        float corr = __expf(m - mnew);
        float e0 = __expf(sc - mnew);
        den = den * corr + e0;
        float2 vv = bf2_to_f2(vu);
        a0 = a0 * corr + e0 * vv.x;
        a1 = a1 * corr + e0 * vv.y;
        m = mnew;
    }
    float r = (end > beg) ? 1.f / fmaxf(den, 1e-16f) : 0.f;
    ((float2*)(agg + (size_t)node * 128))[lane] = make_float2(a0 * r, a1 * r);
}

// ---------------- segment bounds from sorted batch ----------------
__global__ void seg_bounds(const int* __restrict__ batch, int* __restrict__ gstart, int n, int G) {
    int i = blockIdx.x * 256 + threadIdx.x;
    if (i >= n) return;
    int bcur = batch[i];
    int bprev = (i == 0) ? -1 : batch[i - 1];
    for (int g = bprev + 1; g <= bcur; ++g) gstart[g] = i;
    if (i == n - 1)
        for (int g = bcur + 1; g <= G; ++g) gstart[g] = n;
}

// ---------------- pool: one wave per graph ----------------
__global__ __launch_bounds__(256) void pool_kernel(const float* __restrict__ hF, const int* __restrict__ gstart,
                                                   float* __restrict__ pooled, int G) {
    int wave = threadIdx.x >> 6, lane = threadIdx.x & 63;
    int g = blockIdx.x * 4 + wave;
    if (g >= G) return;
    int s = gstart[g], e = gstart[g + 1];
    float a0 = 0.f, a1 = 0.f;
    for (int i = s; i < e; ++i) {
        float2 v = ((const float2*)(hF + (size_t)i * 128))[lane];
        a0 += v.x;
        a1 += v.y;
    }
    ((float2*)(pooled + (size_t)g * 128))[lane] = make_float2(a0, a1);
}

// ---------------- final FC ----------------
__global__ void fc_kernel(const float* __restrict__ pooled, const float* __restrict__ w,
                          const float* __restrict__ bias, float* __restrict__ out, int gcount) {
    int idx = blockIdx.x * blockDim.x + threadIdx.x;
    if (idx >= gcount * 19) return;
    int gi = idx / 19, j = idx % 19;
    float acc = bias[j];
#pragma unroll 8
    for (int k = 0; k < 128; ++k) acc += pooled[(size_t)gi * 128 + k] * w[k * 19 + j];
    out[idx] = acc;
}

extern "C" void kernel_launch(void* const* d_in, const int* in_sizes, int n_in,
                              void* d_out, int out_size, void* d_ws, size_t ws_size,
                              hipStream_t stream) {
    const int* x = (const int*)d_in[0];
    const int* edge_index = (const int*)d_in[1];
    const int* batch = (const int*)d_in[2];
    const float* node_emb = (const float*)d_in[3];
    const float* gcn_w = (const float*)d_in[4];
    const float* gcn_b = (const float*)d_in[5];
    const float* qd_w = (const float*)d_in[6];
    const float* qd_b = (const float*)d_in[7];
    const float* qu_w = (const float*)d_in[8];
    const float* qu_b = (const float*)d_in[9];
    const float* kvd_w = (const float*)d_in[10];
    const float* kvd_b = (const float*)d_in[11];
    const float* ku_w = (const float*)d_in[12];
    const float* ku_b = (const float*)d_in[13];
    const float* vu_w = (const float*)d_in[14];
    const float* vu_b = (const float*)d_in[15];
    const float* ow = (const float*)d_in[16];
    const float* ob = (const float*)d_in[17];
    const float* ln_g = (const float*)d_in[18];
    const float* ln_b = (const float*)d_in[19];
    const float* fc_w = (const float*)d_in[20];
    const float* fc_b = (const float*)d_in[21];
    float* out = (float*)d_out;

    const int N = in_sizes[0] / 11;
    const int E = in_sizes[1] / 2;
    const int G = out_size / 19;
    const int* esrc = edge_index;
    const int* edst = edge_index + E;

    char* ws = (char*)d_ws;
    auto carve = [&](size_t bytes) {
        void* p = (void*)ws;
        ws += WS_ALIGN(bytes);
        return p;
    };
    unsigned short* hB_bf = (unsigned short*)carve((size_t)N * 128 * 2);  // GCN-linear out (bf16)
    float* hC = (float*)carve((size_t)N * 128 * 4);                        // post-GCN residual
    float* q = (float*)carve((size_t)N * 128 * 4);                         // q; reused as hOut
    unsigned short* kv_bf = (unsigned short*)carve((size_t)N * 256 * 2);   // interleaved K|V
    float* agg = (float*)carve((size_t)N * 128 * 4);
    float* q32 = (float*)carve((size_t)N * 32 * 4);
    float* kv32 = (float*)carve((size_t)N * 32 * 4);
    float* dinv = (float*)carve((size_t)N * 4);
    int* cnt = (int*)carve((size_t)N * 4);
    int* fillcnt = (int*)carve((size_t)N * 4);
    int* rowptr = (int*)carve((size_t)(N + 1) * 4);
    int* bsum = (int*)carve(4096);
    int* gstart = (int*)carve((size_t)(G + 1) * 4);
    int* csr_src = (int*)carve((size_t)E * 4);
    float* pooled = (float*)carve((size_t)G * 128 * 4);
    float* hOut = q;  // q dead after attn

    hipMemsetAsync(cnt, 0, (size_t)N * 4, stream);
    hipMemsetAsync(fillcnt, 0, (size_t)N * 4, stream);

    const int nb = (N + 1023) / 1024;

    // 1. GCN linear with fused embedding gather -> hB_bf (bf16)
    gemm_n128<128, 1><<<(N + 63) / 64, 256, 0, stream>>>(nullptr, x, node_emb, gcn_w, nullptr, hB_bf,
                                                         nullptr, nullptr, nullptr, N);

    // 2. degree + CSR (+dinv fused into scan_partial)
    count_kernel<<<(E + 255) / 256, 256, 0, stream>>>(edst, cnt, E);
    scan_partial<<<nb, 256, 0, stream>>>(cnt, rowptr, bsum, dinv, N);
    scan_sums<<<1, 256, 0, stream>>>(bsum, rowptr, nb, N);
    scan_add<<<(N + 255) / 256, 256, 0, stream>>>(rowptr, bsum, N);
    fill_kernel<<<(E + 255) / 256, 256, 0, stream>>>(esrc, edst, rowptr, fillcnt, csr_src, E);

    // 3. GCN aggregate + bias + relu -> hC (residual, f32)
    gcn_agg_kernel<<<(N + 3) / 4, 256, 0, stream>>>(hB_bf, dinv, rowptr, csr_src, gcn_b, hC, N);

    // 4. MLA projections
    gemm_qdkvd<<<(N + 63) / 64, 256, 0, stream>>>(hC, qd_w, kvd_w, qd_b, kvd_b, q32, kv32, N);
    gemm_n128<32, 0><<<(N + 63) / 64, 256, 0, stream>>>(q32, nullptr, nullptr, qu_w, qu_b, q,
                                                        nullptr, nullptr, nullptr, N);
    gemm_kuvu<<<(N + 31) / 32, 256, 0, stream>>>(kv32, ku_w, vu_w, ku_b, vu_b, kv_bf, N);

    // 5. attention
    attn_kernel<<<(N + 3) / 4, 256, 0, stream>>>(q, kv_bf, rowptr, csr_src, agg, N);

    // 6. output projection + residual + LN + ReLU fused -> hOut (aliases q)
    gemm_n128<128, 2><<<(N + 63) / 64, 256, 0, stream>>>(agg, nullptr, nullptr, ow, ob, hOut,
                                                         hC, ln_g, ln_b, N);

    // 7. pool + FC
    seg_bounds<<<(N + 255) / 256, 256, 0, stream>>>(batch, gstart, N, G);
    pool_kernel<<<(G + 3) / 4, 256, 0, stream>>>(hOut, gstart, pooled, G);
    fc_kernel<<<(G * 19 + 255) / 256, 256, 0, stream>>>(pooled, fc_w, fc_b, out, G);
}

// Round 11
// 412.993 us; speedup vs baseline: 2.2210x; 1.0854x over previous
//
#include <hip/hip_runtime.h>
#include <hip/hip_bf16.h>

#define WS_ALIGN(x) (((x) + 255) & ~(size_t)255)

typedef __attribute__((ext_vector_type(8))) short bf16x8;
typedef __attribute__((ext_vector_type(4))) float f32x4;

// ---------- bf16 helpers ----------
__device__ inline unsigned short f2bf(float f) {
    unsigned int u = __float_as_uint(f);
    u = (u + 0x7fffu + ((u >> 16) & 1u)) >> 16;   // RNE
    return (unsigned short)u;
}
__device__ inline float2 bf2_to_f2(unsigned int u) {
    float lo = __uint_as_float((u & 0xffffu) << 16);
    float hi = __uint_as_float(u & 0xffff0000u);
    return make_float2(lo, hi);
}

// =====================================================================
// prep: convert/transpose all weights to bf16 (Wt[col][K]) + emb to bf16
// + concatenated bias buffers. One dispatch, 260 blocks.
// =====================================================================
__global__ __launch_bounds__(256) void prep_kernel(
    const float* __restrict__ ne, const float* __restrict__ gw, const float* __restrict__ oww,
    const float* __restrict__ qd, const float* __restrict__ kvd, const float* __restrict__ quw,
    const float* __restrict__ kuw, const float* __restrict__ vuw,
    const float* __restrict__ qdb, const float* __restrict__ kvdb,
    const float* __restrict__ kub, const float* __restrict__ vub,
    unsigned short* __restrict__ emb_bf, unsigned short* __restrict__ gcnw_t,
    unsigned short* __restrict__ ow_t, unsigned short* __restrict__ qkvd_t,
    unsigned short* __restrict__ quw_t, unsigned short* __restrict__ kvuw_t,
    float* __restrict__ qkv_bias, float* __restrict__ kvu_bias)
{
    int i = blockIdx.x * 256 + threadIdx.x;
    if (i < 12800) { emb_bf[i] = f2bf(ne[i]); return; }
    i -= 12800;
    if (i < 16384) { int k = i >> 7, c = i & 127; gcnw_t[c * 128 + k] = f2bf(gw[i]); return; }
    i -= 16384;
    if (i < 16384) { int k = i >> 7, c = i & 127; ow_t[c * 128 + k] = f2bf(oww[i]); return; }
    i -= 16384;
    if (i < 4096) { int k = i >> 5, c = i & 31; qkvd_t[c * 128 + k] = f2bf(qd[i]); return; }
    i -= 4096;
    if (i < 4096) { int k = i >> 5, c = i & 31; qkvd_t[(c + 32) * 128 + k] = f2bf(kvd[i]); return; }
    i -= 4096;
    if (i < 4096) { int k = i >> 7, c = i & 127; quw_t[c * 32 + k] = f2bf(quw[i]); return; }
    i -= 4096;
    if (i < 4096) { int k = i >> 7, c = i & 127; kvuw_t[c * 32 + k] = f2bf(kuw[i]); return; }
    i -= 4096;
    if (i < 4096) { int k = i >> 7, c = i & 127; kvuw_t[(c + 128) * 32 + k] = f2bf(vuw[i]); return; }
    i -= 4096;
    if (i < 64) { qkv_bias[i] = (i < 32) ? qdb[i] : kvdb[i - 32]; return; }
    i -= 64;
    if (i < 256) { kvu_bias[i] = (i < 128) ? kub[i] : vub[i - 128]; return; }
}

// =====================================================================
// MFMA GEMM: out[n,NCOL] = A[n,K] @ W[K,NCOL] (+bias), bf16 MFMA 16x16x32.
// A source: embedding-gather bf16 (xidx), direct bf16 (Abf), or f32 (Af32).
// Wt = transposed bf16 weights [NCOL][K] read from global (L2-resident).
// Block 256 = 4 waves; tile 64 rows; wave w owns rows [16w,16w+16).
// MODE: 0 = f32 out, 1 = bf16 out, 2 = f32 + fused residual+LN+ReLU.
// C/D layout (m89): col = lane&15, row = (lane>>4)*4 + reg.
// =====================================================================
template <int K, int NCOL, int MODE>
__global__ __launch_bounds__(256) void gemm_mfma(
    const unsigned short* __restrict__ Abf, const float* __restrict__ Af32,
    const int* __restrict__ xidx, const unsigned short* __restrict__ embbf,
    int ldA, const unsigned short* __restrict__ Wt, const float* __restrict__ bias,
    void* __restrict__ outp, const float* __restrict__ res,
    const float* __restrict__ lng, const float* __restrict__ lnb, int n)
{
    constexpr int CPR = K / 8;                       // 16B chunks per row
    constexpr int SWZ = (CPR >= 8) ? 7 : (CPR - 1);  // row-XOR swizzle mask
    constexpr int CPT = (64 * CPR) / 256;            // chunks staged per thread
    __shared__ unsigned short As[64 * K];
    const int tid = threadIdx.x;
    const int row0 = blockIdx.x * 64;
    // ---- stage A tile (bf16, swizzled 16B chunks) ----
#pragma unroll
    for (int i = 0; i < CPT; ++i) {
        int chunk = tid + i * 256;
        int r = chunk / CPR, c = chunk % CPR;
        int row = row0 + r;
        int csw = c ^ (r & SWZ);
        unsigned short tmp[8];
        if (row < n) {
            if (xidx) {
                *(int4*)tmp = *(const int4*)(embbf + ((size_t)xidx[row * 11] << 7) + c * 8);
            } else if (Abf) {
                *(int4*)tmp = *(const int4*)(Abf + (size_t)row * ldA + c * 8);
            } else {
                const float* src = Af32 + (size_t)row * ldA + c * 8;
                float4 f0 = *(const float4*)src;
                float4 f1 = *(const float4*)(src + 4);
                tmp[0] = f2bf(f0.x); tmp[1] = f2bf(f0.y); tmp[2] = f2bf(f0.z); tmp[3] = f2bf(f0.w);
                tmp[4] = f2bf(f1.x); tmp[5] = f2bf(f1.y); tmp[6] = f2bf(f1.z); tmp[7] = f2bf(f1.w);
            }
        } else {
#pragma unroll
            for (int j = 0; j < 8; ++j) tmp[j] = 0;
        }
        *(int4*)&As[(r * CPR + csw) * 8] = *(int4*)tmp;
    }
    __syncthreads();
    const int wave = tid >> 6, lane = tid & 63;
    const int qtr = lane >> 4, l16 = lane & 15;
    const int arow = wave * 16 + l16;     // A-frag row within block tile
    constexpr int NT = NCOL / 16;
    f32x4 acc[NT] = {};
    for (int ks = 0; ks < K / 32; ++ks) {
        int c = ks * 4 + qtr;
        int csw = c ^ (arow & SWZ);
        bf16x8 af = *(const bf16x8*)&As[(arow * CPR + csw) * 8];
#pragma unroll
        for (int t = 0; t < NT; ++t) {
            bf16x8 bf = *(const bf16x8*)(Wt + (size_t)(t * 16 + l16) * K + ks * 32 + qtr * 8);
            acc[t] = __builtin_amdgcn_mfma_f32_16x16x32_bf16(af, bf, acc[t], 0, 0, 0);
        }
    }
    if constexpr (MODE == 2) {
        // fused: + bias + residual, LayerNorm over 128 cols, ReLU
        float vals[NT][4];
#pragma unroll
        for (int t = 0; t < NT; ++t) {
            int col = t * 16 + l16;
            float ob_ = bias[col];
#pragma unroll
            for (int rg = 0; rg < 4; ++rg) {
                int row = row0 + wave * 16 + qtr * 4 + rg;
                float rr = (row < n) ? res[(size_t)row * 128 + col] : 0.f;
                vals[t][rg] = acc[t][rg] + ob_ + rr;
            }
        }
#pragma unroll
        for (int rg = 0; rg < 4; ++rg) {
            int row = row0 + wave * 16 + qtr * 4 + rg;   // quarter-uniform
            if (row < n) {
                float s = 0.f;
#pragma unroll
                for (int t = 0; t < NT; ++t) s += vals[t][rg];
                s += __shfl_xor(s, 1); s += __shfl_xor(s, 2);
                s += __shfl_xor(s, 4); s += __shfl_xor(s, 8);
                float mu = s * (1.f / 128.f);
                float vs = 0.f;
#pragma unroll
                for (int t = 0; t < NT; ++t) { float d = vals[t][rg] - mu; vs += d * d; }
                vs += __shfl_xor(vs, 1); vs += __shfl_xor(vs, 2);
                vs += __shfl_xor(vs, 4); vs += __shfl_xor(vs, 8);
                float rstd = rsqrtf(vs * (1.f / 128.f) + 1e-5f);
#pragma unroll
                for (int t = 0; t < NT; ++t) {
                    int col = t * 16 + l16;
                    float y = fmaxf((vals[t][rg] - mu) * rstd * lng[col] + lnb[col], 0.f);
                    ((float*)outp)[(size_t)row * 128 + col] = y;
                }
            }
        }
    } else {
#pragma unroll
        for (int t = 0; t < NT; ++t) {
            int col = t * 16 + l16;
            float b = bias ? bias[col] : 0.f;
#pragma unroll
            for (int rg = 0; rg < 4; ++rg) {
                int row = row0 + wave * 16 + qtr * 4 + rg;
                if (row < n) {
                    float v = acc[t][rg] + b;
                    if constexpr (MODE == 1)
                        ((unsigned short*)outp)[(size_t)row * NCOL + col] = f2bf(v);
                    else
                        ((float*)outp)[(size_t)row * NCOL + col] = v;
                }
            }
        }
    }
}

// ---------------- in-degree count ----------------
__global__ void count_kernel(const int* __restrict__ dst, int* __restrict__ cnt, int e) {
    int t = blockIdx.x * blockDim.x + threadIdx.x;
    if (t < e) atomicAdd(&cnt[dst[t]], 1);
}

// ---------------- parallel scan (1024/block) + fused dinv ----------------
__global__ __launch_bounds__(256) void scan_partial(const int* __restrict__ cnt, int* __restrict__ rowptr,
                                                    int* __restrict__ bsum, float* __restrict__ dinv, int n) {
    __shared__ int wsum[4];
    int tid = threadIdx.x, lane = tid & 63, wid = tid >> 6;
    int i0 = blockIdx.x * 1024 + tid * 4;
    int e0 = 0, e1 = 0, e2 = 0, e3 = 0;
    if (i0 + 3 < n) {
        int4 v4 = *(const int4*)(cnt + i0);
        e0 = v4.x; e1 = v4.y; e2 = v4.z; e3 = v4.w;
    } else {
        if (i0 < n) e0 = cnt[i0];
        if (i0 + 1 < n) e1 = cnt[i0 + 1];
        if (i0 + 2 < n) e2 = cnt[i0 + 2];
    }
    int s = e0 + e1 + e2 + e3;
    int sc = s;
#pragma unroll
    for (int o = 1; o < 64; o <<= 1) {
        int t = __shfl_up(sc, o);
        if (lane >= o) sc += t;
    }
    if (lane == 63) wsum[wid] = sc;
    __syncthreads();
    int woff = 0;
#pragma unroll
    for (int w = 0; w < 4; ++w)
        if (w < wid) woff += wsum[w];
    int ex = woff + sc - s;
    if (i0 < n)     { rowptr[i0] = ex;                    dinv[i0] = rsqrtf((float)e0 + 1.f); }
    if (i0 + 1 < n) { rowptr[i0 + 1] = ex + e0;           dinv[i0 + 1] = rsqrtf((float)e1 + 1.f); }
    if (i0 + 2 < n) { rowptr[i0 + 2] = ex + e0 + e1;      dinv[i0 + 2] = rsqrtf((float)e2 + 1.f); }
    if (i0 + 3 < n) { rowptr[i0 + 3] = ex + e0 + e1 + e2; dinv[i0 + 3] = rsqrtf((float)e3 + 1.f); }
    if (tid == 255) bsum[blockIdx.x] = woff + sc;
}

// ---------------- scan block sums (nb <= 256) ----------------
__global__ __launch_bounds__(256) void scan_sums(int* __restrict__ bsum, int* __restrict__ rowptr, int nb, int n) {
    __shared__ int wsum[4];
    int tid = threadIdx.x, lane = tid & 63, wid = tid >> 6;
    int v = (tid < nb) ? bsum[tid] : 0;
    int sc = v;
#pragma unroll
    for (int o = 1; o < 64; o <<= 1) {
        int t = __shfl_up(sc, o);
        if (lane >= o) sc += t;
    }
    if (lane == 63) wsum[wid] = sc;
    __syncthreads();
    int woff = 0;
#pragma unroll
    for (int w = 0; w < 4; ++w)
        if (w < wid) woff += wsum[w];
    if (tid < nb) bsum[tid] = woff + sc - v;
    if (tid == 255) rowptr[n] = woff + sc;
}

__global__ void scan_add(int* __restrict__ rowptr, const int* __restrict__ bsum, int n) {
    int i = blockIdx.x * 256 + threadIdx.x;
    if (i < n) rowptr[i] += bsum[i >> 10];
}

// ---------------- CSR fill ----------------
__global__ void fill_kernel(const int* __restrict__ src, const int* __restrict__ dst,
                            const int* __restrict__ rowptr, int* __restrict__ fillcnt,
                            int* __restrict__ csr_src, int e) {
    int t = blockIdx.x * blockDim.x + threadIdx.x;
    if (t >= e) return;
    int d = dst[t];
    int pos = rowptr[d] + atomicAdd(&fillcnt[d], 1);
    csr_src[pos] = src[t];
}

// ---------------- GCN aggregate (bf16 gather) -> hC f32 + hC bf16 ----------------
__global__ __launch_bounds__(256) void gcn_agg_kernel(const unsigned short* __restrict__ hl, const float* __restrict__ dinv,
                                                      const int* __restrict__ rowptr, const int* __restrict__ csr_src,
                                                      const float* __restrict__ bias, float* __restrict__ out,
                                                      unsigned short* __restrict__ out_bf, int n) {
    int wave = threadIdx.x >> 6, lane = threadIdx.x & 63;
    int node = blockIdx.x * 4 + wave;
    if (node >= n) return;
    float dn = dinv[node];
    float2 sv = bf2_to_f2(((const unsigned int*)(hl + (size_t)node * 128))[lane]);
    float a0 = sv.x * dn * dn, a1 = sv.y * dn * dn;
    int beg = rowptr[node], end = rowptr[node + 1];
    int idx = beg;
    for (; idx + 4 <= end; idx += 4) {
        int s0 = csr_src[idx], s1 = csr_src[idx + 1], s2 = csr_src[idx + 2], s3 = csr_src[idx + 3];
        unsigned int u0 = ((const unsigned int*)(hl + (size_t)s0 * 128))[lane];
        unsigned int u1 = ((const unsigned int*)(hl + (size_t)s1 * 128))[lane];
        unsigned int u2 = ((const unsigned int*)(hl + (size_t)s2 * 128))[lane];
        unsigned int u3 = ((const unsigned int*)(hl + (size_t)s3 * 128))[lane];
        float w0 = dinv[s0] * dn, w1 = dinv[s1] * dn, w2 = dinv[s2] * dn, w3 = dinv[s3] * dn;
        float2 h0 = bf2_to_f2(u0), h1 = bf2_to_f2(u1), h2 = bf2_to_f2(u2), h3 = bf2_to_f2(u3);
        a0 += h0.x * w0 + h1.x * w1 + h2.x * w2 + h3.x * w3;
        a1 += h0.y * w0 + h1.y * w1 + h2.y * w2 + h3.y * w3;
    }
    for (; idx < end; ++idx) {
        int s = csr_src[idx];
        float w = dinv[s] * dn;
        float2 h = bf2_to_f2(((const unsigned int*)(hl + (size_t)s * 128))[lane]);
        a0 += h.x * w;
        a1 += h.y * w;
    }
    int d0 = lane * 2;
    a0 = fmaxf(a0 + bias[d0], 0.f);
    a1 = fmaxf(a1 + bias[d0 + 1], 0.f);
    ((float2*)(out + (size_t)node * 128))[lane] = make_float2(a0, a1);
    ((unsigned int*)(out_bf + (size_t)node * 128))[lane] = (unsigned int)f2bf(a0) | ((unsigned int)f2bf(a1) << 16);
}

// ---------------- MLA attention: no-max softmax (scores ~1e-6), bf16 out ----------------
__global__ __launch_bounds__(256) void attn_kernel(const float* __restrict__ q, const unsigned short* __restrict__ kv,
                                                   const int* __restrict__ rowptr, const int* __restrict__ csr_src,
                                                   unsigned short* __restrict__ agg_bf, int n) {
    int wave = threadIdx.x >> 6, lane = threadIdx.x & 63;
    int node = blockIdx.x * 4 + wave;
    if (node >= n) return;
    float2 qv = ((const float2*)(q + (size_t)node * 128))[lane];
    int beg = rowptr[node], end = rowptr[node + 1];
    float den = 0.f, a0 = 0.f, a1 = 0.f;
    int idx = beg;
    for (; idx + 4 <= end; idx += 4) {
        int s0 = csr_src[idx], s1 = csr_src[idx + 1], s2 = csr_src[idx + 2], s3 = csr_src[idx + 3];
        const unsigned int* r0 = (const unsigned int*)(kv + (size_t)s0 * 256);
        const unsigned int* r1 = (const unsigned int*)(kv + (size_t)s1 * 256);
        const unsigned int* r2 = (const unsigned int*)(kv + (size_t)s2 * 256);
        const unsigned int* r3 = (const unsigned int*)(kv + (size_t)s3 * 256);
        unsigned int ku0 = r0[lane], vu0 = r0[64 + lane];
        unsigned int ku1 = r1[lane], vu1 = r1[64 + lane];
        unsigned int ku2 = r2[lane], vu2 = r2[64 + lane];
        unsigned int ku3 = r3[lane], vu3 = r3[64 + lane];
        float2 k0 = bf2_to_f2(ku0), k1 = bf2_to_f2(ku1), k2 = bf2_to_f2(ku2), k3 = bf2_to_f2(ku3);
        float p0 = qv.x * k0.x + qv.y * k0.y;
        float p1 = qv.x * k1.x + qv.y * k1.y;
        float p2 = qv.x * k2.x + qv.y * k2.y;
        float p3 = qv.x * k3.x + qv.y * k3.y;
        p0 += __shfl_xor(p0, 1); p1 += __shfl_xor(p1, 1); p2 += __shfl_xor(p2, 1); p3 += __shfl_xor(p3, 1);
        p0 += __shfl_xor(p0, 2); p1 += __shfl_xor(p1, 2); p2 += __shfl_xor(p2, 2); p3 += __shfl_xor(p3, 2);
        p0 += __shfl_xor(p0, 4); p1 += __shfl_xor(p1, 4); p2 += __shfl_xor(p2, 4); p3 += __shfl_xor(p3, 4);
        float e0 = __expf(p0 * 0.25f), e1 = __expf(p1 * 0.25f);
        float e2 = __expf(p2 * 0.25f), e3 = __expf(p3 * 0.25f);
        den += (e0 + e1) + (e2 + e3);
        float2 v0 = bf2_to_f2(vu0), v1 = bf2_to_f2(vu1), v2 = bf2_to_f2(vu2), v3 = bf2_to_f2(vu3);
        a0 += e0 * v0.x + e1 * v1.x + e2 * v2.x + e3 * v3.x;
        a1 += e0 * v0.y + e1 * v1.y + e2 * v2.y + e3 * v3.y;
    }
    for (; idx < end; ++idx) {
        int s = csr_src[idx];
        const unsigned int* r = (const unsigned int*)(kv + (size_t)s * 256);
        unsigned int ku = r[lane], vu = r[64 + lane];
        float2 kvv = bf2_to_f2(ku);
        float p = qv.x * kvv.x + qv.y * kvv.y;
        p += __shfl_xor(p, 1);
        p += __shfl_xor(p, 2);
        p += __shfl_xor(p, 4);
        float e0 = __expf(p * 0.25f);
        den += e0;
        float2 vv = bf2_to_f2(vu);
        a0 += e0 * vv.x;
        a1 += e0 * vv.y;
    }
    float r = (end > beg) ? 1.f / fmaxf(den, 1e-16f) : 0.f;
    ((unsigned int*)(agg_bf + (size_t)node * 128))[lane] =
        (unsigned int)f2bf(a0 * r) | ((unsigned int)f2bf(a1 * r) << 16);
}

// ---------------- segment bounds from sorted batch ----------------
__global__ void seg_bounds(const int* __restrict__ batch, int* __restrict__ gstart, int n, int G) {
    int i = blockIdx.x * 256 + threadIdx.x;
    if (i >= n) return;
    int bcur = batch[i];
    int bprev = (i == 0) ? -1 : batch[i - 1];
    for (int g = bprev + 1; g <= bcur; ++g) gstart[g] = i;
    if (i == n - 1)
        for (int g = bcur + 1; g <= G; ++g) gstart[g] = n;
}

// ---------------- pool: one wave per graph ----------------
__global__ __launch_bounds__(256) void pool_kernel(const float* __restrict__ hF, const int* __restrict__ gstart,
                                                   float* __restrict__ pooled, int G) {
    int wave = threadIdx.x >> 6, lane = threadIdx.x & 63;
    int g = blockIdx.x * 4 + wave;
    if (g >= G) return;
    int s = gstart[g], e = gstart[g + 1];
    float a0 = 0.f, a1 = 0.f;
    for (int i = s; i < e; ++i) {
        float2 v = ((const float2*)(hF + (size_t)i * 128))[lane];
        a0 += v.x;
        a1 += v.y;
    }
    ((float2*)(pooled + (size_t)g * 128))[lane] = make_float2(a0, a1);
}

// ---------------- final FC ----------------
__global__ void fc_kernel(const float* __restrict__ pooled, const float* __restrict__ w,
                          const float* __restrict__ bias, float* __restrict__ out, int gcount) {
    int idx = blockIdx.x * blockDim.x + threadIdx.x;
    if (idx >= gcount * 19) return;
    int gi = idx / 19, j = idx % 19;
    float acc = bias[j];
#pragma unroll 8
    for (int k = 0; k < 128; ++k) acc += pooled[(size_t)gi * 128 + k] * w[k * 19 + j];
    out[idx] = acc;
}

extern "C" void kernel_launch(void* const* d_in, const int* in_sizes, int n_in,
                              void* d_out, int out_size, void* d_ws, size_t ws_size,
                              hipStream_t stream) {
    const int* x = (const int*)d_in[0];
    const int* edge_index = (const int*)d_in[1];
    const int* batch = (const int*)d_in[2];
    const float* node_emb = (const float*)d_in[3];
    const float* gcn_w = (const float*)d_in[4];
    const float* gcn_b = (const float*)d_in[5];
    const float* qd_w = (const float*)d_in[6];
    const float* qd_b = (const float*)d_in[7];
    const float* qu_w = (const float*)d_in[8];
    const float* qu_b = (const float*)d_in[9];
    const float* kvd_w = (const float*)d_in[10];
    const float* kvd_b = (const float*)d_in[11];
    const float* ku_w = (const float*)d_in[12];
    const float* ku_b = (const float*)d_in[13];
    const float* vu_w = (const float*)d_in[14];
    const float* vu_b = (const float*)d_in[15];
    const float* ow = (const float*)d_in[16];
    const float* ob = (const float*)d_in[17];
    const float* ln_g = (const float*)d_in[18];
    const float* ln_b = (const float*)d_in[19];
    const float* fc_w = (const float*)d_in[20];
    const float* fc_b = (const float*)d_in[21];
    float* out = (float*)d_out;

    const int N = in_sizes[0] / 11;
    const int E = in_sizes[1] / 2;
    const int G = out_size / 19;
    const int* esrc = edge_index;
    const int* edst = edge_index + E;

    char* ws = (char*)d_ws;
    auto carve = [&](size_t bytes) {
        void* p = (void*)ws;
        ws += WS_ALIGN(bytes);
        return p;
    };
    // weights (bf16 transposed)
    unsigned short* emb_bf = (unsigned short*)carve(12800 * 2);
    unsigned short* gcnw_t = (unsigned short*)carve(16384 * 2);
    unsigned short* ow_t = (unsigned short*)carve(16384 * 2);
    unsigned short* qkvd_t = (unsigned short*)carve(8192 * 2);
    unsigned short* quw_t = (unsigned short*)carve(4096 * 2);
    unsigned short* kvuw_t = (unsigned short*)carve(8192 * 2);
    float* qkv_bias = (float*)carve(64 * 4);
    float* kvu_bias = (float*)carve(256 * 4);
    // activations
    unsigned short* hB_bf = (unsigned short*)carve((size_t)N * 128 * 2);  // GCN-linear out
    float* hC = (float*)carve((size_t)N * 128 * 4);                        // residual (f32)
    unsigned short* hC_bf = (unsigned short*)carve((size_t)N * 128 * 2);  // qdkvd input
    float* q = (float*)carve((size_t)N * 128 * 4);                         // q; reused as hOut
    unsigned short* kv_bf = (unsigned short*)carve((size_t)N * 256 * 2);  // interleaved K|V
    float* dinv = (float*)carve((size_t)N * 4);
    int* cnt = (int*)carve((size_t)N * 4);
    int* fillcnt = (int*)carve((size_t)N * 4);
    int* rowptr = (int*)carve((size_t)(N + 1) * 4);
    int* bsum = (int*)carve(4096);
    int* gstart = (int*)carve((size_t)(G + 1) * 4);
    int* csr_src = (int*)carve((size_t)E * 4);
    float* pooled = (float*)carve((size_t)G * 128 * 4);
    // aliases (stream-ordered lifetime-disjoint)
    float* qkv64 = (float*)hB_bf;              // N*64 f32 == N*128 bf16; hB_bf dead after gcn_agg
    unsigned short* agg_bf = hC_bf;            // hC_bf dead after qdkvd; agg written by attn
    float* hOut = q;                           // q dead after attn

    hipMemsetAsync(cnt, 0, (size_t)N * 4, stream);
    hipMemsetAsync(fillcnt, 0, (size_t)N * 4, stream);

    const int nb = (N + 1023) / 1024;
    const int gb = (N + 63) / 64;

    // 0. weight prep (bf16 transposed + biases)
    prep_kernel<<<260, 256, 0, stream>>>(node_emb, gcn_w, ow, qd_w, kvd_w, qu_w, ku_w, vu_w,
                                         qd_b, kvd_b, ku_b, vu_b,
                                         emb_bf, gcnw_t, ow_t, qkvd_t, quw_t, kvuw_t, qkv_bias, kvu_bias);

    // 1. GCN linear (embedding-gather A) -> hB_bf
    gemm_mfma<128, 128, 1><<<gb, 256, 0, stream>>>(nullptr, nullptr, x, emb_bf, 128, gcnw_t,
                                                   nullptr, hB_bf, nullptr, nullptr, nullptr, N);

    // 2. degree + CSR
    count_kernel<<<(E + 255) / 256, 256, 0, stream>>>(edst, cnt, E);
    scan_partial<<<nb, 256, 0, stream>>>(cnt, rowptr, bsum, dinv, N);
    scan_sums<<<1, 256, 0, stream>>>(bsum, rowptr, nb, N);
    scan_add<<<(N + 255) / 256, 256, 0, stream>>>(rowptr, bsum, N);
    fill_kernel<<<(E + 255) / 256, 256, 0, stream>>>(esrc, edst, rowptr, fillcnt, csr_src, E);

    // 3. GCN aggregate -> hC (f32) + hC_bf
    gcn_agg_kernel<<<(N + 3) / 4, 256, 0, stream>>>(hB_bf, dinv, rowptr, csr_src, gcn_b, hC, hC_bf, N);

    // 4. MLA projections (all MFMA)
    gemm_mfma<128, 64, 0><<<gb, 256, 0, stream>>>(hC_bf, nullptr, nullptr, nullptr, 128, qkvd_t,
                                                  qkv_bias, qkv64, nullptr, nullptr, nullptr, N);
    gemm_mfma<32, 128, 0><<<gb, 256, 0, stream>>>(nullptr, qkv64, nullptr, nullptr, 64, quw_t,
                                                  qu_b, q, nullptr, nullptr, nullptr, N);
    gemm_mfma<32, 256, 1><<<gb, 256, 0, stream>>>(nullptr, qkv64 + 32, nullptr, nullptr, 64, kvuw_t,
                                                  kvu_bias, kv_bf, nullptr, nullptr, nullptr, N);

    // 5. attention (no-max softmax) -> agg_bf
    attn_kernel<<<(N + 3) / 4, 256, 0, stream>>>(q, kv_bf, rowptr, csr_src, agg_bf, N);

    // 6. output projection + residual + LN + ReLU fused -> hOut
    gemm_mfma<128, 128, 2><<<gb, 256, 0, stream>>>(agg_bf, nullptr, nullptr, nullptr, 128, ow_t,
                                                   ob, hOut, hC, ln_g, ln_b, N);

    // 7. pool + FC
    seg_bounds<<<(N + 255) / 256, 256, 0, stream>>>(batch, gstart, N, G);
    pool_kernel<<<(G + 3) / 4, 256, 0, stream>>>(hOut, gstart, pooled, G);
    fc_kernel<<<(G * 19 + 255) / 256, 256, 0, stream>>>(pooled, fc_w, fc_b, out, G);
}

// Round 12
// 406.222 us; speedup vs baseline: 2.2581x; 1.0167x over previous
//
#include <hip/hip_runtime.h>
#include <hip/hip_bf16.h>

#define WS_ALIGN(x) (((x) + 255) & ~(size_t)255)

typedef __attribute__((ext_vector_type(8))) short bf16x8;
typedef __attribute__((ext_vector_type(4))) float f32x4;

// ---------- bf16 helpers ----------
__device__ inline unsigned short f2bf(float f) {
    unsigned int u = __float_as_uint(f);
    u = (u + 0x7fffu + ((u >> 16) & 1u)) >> 16;   // RNE
    return (unsigned short)u;
}
__device__ inline float2 bf2_to_f2(unsigned int u) {
    float lo = __uint_as_float((u & 0xffffu) << 16);
    float hi = __uint_as_float(u & 0xffff0000u);
    return make_float2(lo, hi);
}

// =====================================================================
// prep: convert/transpose all weights to bf16 (Wt[col][K]) + emb to bf16
// =====================================================================
__global__ __launch_bounds__(256) void prep_kernel(
    const float* __restrict__ ne, const float* __restrict__ gw, const float* __restrict__ oww,
    const float* __restrict__ qd, const float* __restrict__ kvd, const float* __restrict__ quw,
    const float* __restrict__ kuw, const float* __restrict__ vuw,
    const float* __restrict__ qdb, const float* __restrict__ kvdb,
    const float* __restrict__ kub, const float* __restrict__ vub,
    unsigned short* __restrict__ emb_bf, unsigned short* __restrict__ gcnw_t,
    unsigned short* __restrict__ ow_t, unsigned short* __restrict__ qkvd_t,
    unsigned short* __restrict__ quw_t, unsigned short* __restrict__ kvuw_t,
    float* __restrict__ qkv_bias, float* __restrict__ kvu_bias)
{
    int i = blockIdx.x * 256 + threadIdx.x;
    if (i < 12800) { emb_bf[i] = f2bf(ne[i]); return; }
    i -= 12800;
    if (i < 16384) { int k = i >> 7, c = i & 127; gcnw_t[c * 128 + k] = f2bf(gw[i]); return; }
    i -= 16384;
    if (i < 16384) { int k = i >> 7, c = i & 127; ow_t[c * 128 + k] = f2bf(oww[i]); return; }
    i -= 16384;
    if (i < 4096) { int k = i >> 5, c = i & 31; qkvd_t[c * 128 + k] = f2bf(qd[i]); return; }
    i -= 4096;
    if (i < 4096) { int k = i >> 5, c = i & 31; qkvd_t[(c + 32) * 128 + k] = f2bf(kvd[i]); return; }
    i -= 4096;
    if (i < 4096) { int k = i >> 7, c = i & 127; quw_t[c * 32 + k] = f2bf(quw[i]); return; }
    i -= 4096;
    if (i < 4096) { int k = i >> 7, c = i & 127; kvuw_t[c * 32 + k] = f2bf(kuw[i]); return; }
    i -= 4096;
    if (i < 4096) { int k = i >> 7, c = i & 127; kvuw_t[(c + 128) * 32 + k] = f2bf(vuw[i]); return; }
    i -= 4096;
    if (i < 64) { qkv_bias[i] = (i < 32) ? qdb[i] : kvdb[i - 32]; return; }
    i -= 64;
    if (i < 256) { kvu_bias[i] = (i < 128) ? kub[i] : vub[i - 128]; return; }
}

// =====================================================================
// MFMA GEMM (16x16x32 bf16), same structure as R11 (measured good).
// =====================================================================
template <int K, int NCOL, int MODE>
__global__ __launch_bounds__(256) void gemm_mfma(
    const unsigned short* __restrict__ Abf, const float* __restrict__ Af32,
    const int* __restrict__ xidx, const unsigned short* __restrict__ embbf,
    int ldA, const unsigned short* __restrict__ Wt, const float* __restrict__ bias,
    void* __restrict__ outp, const float* __restrict__ res,
    const float* __restrict__ lng, const float* __restrict__ lnb, int n)
{
    constexpr int CPR = K / 8;
    constexpr int SWZ = (CPR >= 8) ? 7 : (CPR - 1);
    constexpr int CPT = (64 * CPR) / 256;
    __shared__ unsigned short As[64 * K];
    const int tid = threadIdx.x;
    const int row0 = blockIdx.x * 64;
#pragma unroll
    for (int i = 0; i < CPT; ++i) {
        int chunk = tid + i * 256;
        int r = chunk / CPR, c = chunk % CPR;
        int row = row0 + r;
        int csw = c ^ (r & SWZ);
        unsigned short tmp[8];
        if (row < n) {
            if (xidx) {
                *(int4*)tmp = *(const int4*)(embbf + ((size_t)xidx[row * 11] << 7) + c * 8);
            } else if (Abf) {
                *(int4*)tmp = *(const int4*)(Abf + (size_t)row * ldA + c * 8);
            } else {
                const float* src = Af32 + (size_t)row * ldA + c * 8;
                float4 f0 = *(const float4*)src;
                float4 f1 = *(const float4*)(src + 4);
                tmp[0] = f2bf(f0.x); tmp[1] = f2bf(f0.y); tmp[2] = f2bf(f0.z); tmp[3] = f2bf(f0.w);
                tmp[4] = f2bf(f1.x); tmp[5] = f2bf(f1.y); tmp[6] = f2bf(f1.z); tmp[7] = f2bf(f1.w);
            }
        } else {
#pragma unroll
            for (int j = 0; j < 8; ++j) tmp[j] = 0;
        }
        *(int4*)&As[(r * CPR + csw) * 8] = *(int4*)tmp;
    }
    __syncthreads();
    const int wave = tid >> 6, lane = tid & 63;
    const int qtr = lane >> 4, l16 = lane & 15;
    const int arow = wave * 16 + l16;
    constexpr int NT = NCOL / 16;
    f32x4 acc[NT] = {};
    for (int ks = 0; ks < K / 32; ++ks) {
        int c = ks * 4 + qtr;
        int csw = c ^ (arow & SWZ);
        bf16x8 af = *(const bf16x8*)&As[(arow * CPR + csw) * 8];
#pragma unroll
        for (int t = 0; t < NT; ++t) {
            bf16x8 bf = *(const bf16x8*)(Wt + (size_t)(t * 16 + l16) * K + ks * 32 + qtr * 8);
            acc[t] = __builtin_amdgcn_mfma_f32_16x16x32_bf16(af, bf, acc[t], 0, 0, 0);
        }
    }
    if constexpr (MODE == 2) {
        float vals[NT][4];
#pragma unroll
        for (int t = 0; t < NT; ++t) {
            int col = t * 16 + l16;
            float ob_ = bias[col];
#pragma unroll
            for (int rg = 0; rg < 4; ++rg) {
                int row = row0 + wave * 16 + qtr * 4 + rg;
                float rr = (row < n) ? res[(size_t)row * 128 + col] : 0.f;
                vals[t][rg] = acc[t][rg] + ob_ + rr;
            }
        }
#pragma unroll
        for (int rg = 0; rg < 4; ++rg) {
            int row = row0 + wave * 16 + qtr * 4 + rg;
            if (row < n) {
                float s = 0.f;
#pragma unroll
                for (int t = 0; t < NT; ++t) s += vals[t][rg];
                s += __shfl_xor(s, 1); s += __shfl_xor(s, 2);
                s += __shfl_xor(s, 4); s += __shfl_xor(s, 8);
                float mu = s * (1.f / 128.f);
                float vs = 0.f;
#pragma unroll
                for (int t = 0; t < NT; ++t) { float d = vals[t][rg] - mu; vs += d * d; }
                vs += __shfl_xor(vs, 1); vs += __shfl_xor(vs, 2);
                vs += __shfl_xor(vs, 4); vs += __shfl_xor(vs, 8);
                float rstd = rsqrtf(vs * (1.f / 128.f) + 1e-5f);
#pragma unroll
                for (int t = 0; t < NT; ++t) {
                    int col = t * 16 + l16;
                    float y = fmaxf((vals[t][rg] - mu) * rstd * lng[col] + lnb[col], 0.f);
                    ((float*)outp)[(size_t)row * 128 + col] = y;
                }
            }
        }
    } else {
#pragma unroll
        for (int t = 0; t < NT; ++t) {
            int col = t * 16 + l16;
            float b = bias ? bias[col] : 0.f;
#pragma unroll
            for (int rg = 0; rg < 4; ++rg) {
                int row = row0 + wave * 16 + qtr * 4 + rg;
                if (row < n) {
                    float v = acc[t][rg] + b;
                    if constexpr (MODE == 1)
                        ((unsigned short*)outp)[(size_t)row * NCOL + col] = f2bf(v);
                    else
                        ((float*)outp)[(size_t)row * NCOL + col] = v;
                }
            }
        }
    }
}

// ---------------- in-degree count ----------------
__global__ void count_kernel(const int* __restrict__ dst, int* __restrict__ cnt, int e) {
    int t = blockIdx.x * blockDim.x + threadIdx.x;
    if (t < e) atomicAdd(&cnt[dst[t]], 1);
}

// ---------------- parallel scan (1024/block) + fused dinv ----------------
__global__ __launch_bounds__(256) void scan_partial(const int* __restrict__ cnt, int* __restrict__ rowptr,
                                                    int* __restrict__ bsum, float* __restrict__ dinv, int n) {
    __shared__ int wsum[4];
    int tid = threadIdx.x, lane = tid & 63, wid = tid >> 6;
    int i0 = blockIdx.x * 1024 + tid * 4;
    int e0 = 0, e1 = 0, e2 = 0, e3 = 0;
    if (i0 + 3 < n) {
        int4 v4 = *(const int4*)(cnt + i0);
        e0 = v4.x; e1 = v4.y; e2 = v4.z; e3 = v4.w;
    } else {
        if (i0 < n) e0 = cnt[i0];
        if (i0 + 1 < n) e1 = cnt[i0 + 1];
        if (i0 + 2 < n) e2 = cnt[i0 + 2];
    }
    int s = e0 + e1 + e2 + e3;
    int sc = s;
#pragma unroll
    for (int o = 1; o < 64; o <<= 1) {
        int t = __shfl_up(sc, o);
        if (lane >= o) sc += t;
    }
    if (lane == 63) wsum[wid] = sc;
    __syncthreads();
    int woff = 0;
#pragma unroll
    for (int w = 0; w < 4; ++w)
        if (w < wid) woff += wsum[w];
    int ex = woff + sc - s;
    if (i0 < n)     { rowptr[i0] = ex;                    dinv[i0] = rsqrtf((float)e0 + 1.f); }
    if (i0 + 1 < n) { rowptr[i0 + 1] = ex + e0;           dinv[i0 + 1] = rsqrtf((float)e1 + 1.f); }
    if (i0 + 2 < n) { rowptr[i0 + 2] = ex + e0 + e1;      dinv[i0 + 2] = rsqrtf((float)e2 + 1.f); }
    if (i0 + 3 < n) { rowptr[i0 + 3] = ex + e0 + e1 + e2; dinv[i0 + 3] = rsqrtf((float)e3 + 1.f); }
    if (tid == 255) bsum[blockIdx.x] = woff + sc;
}

// ---------------- scan block sums (nb <= 256) ----------------
__global__ __launch_bounds__(256) void scan_sums(int* __restrict__ bsum, int* __restrict__ rowptr, int nb, int n) {
    __shared__ int wsum[4];
    int tid = threadIdx.x, lane = tid & 63, wid = tid >> 6;
    int v = (tid < nb) ? bsum[tid] : 0;
    int sc = v;
#pragma unroll
    for (int o = 1; o < 64; o <<= 1) {
        int t = __shfl_up(sc, o);
        if (lane >= o) sc += t;
    }
    if (lane == 63) wsum[wid] = sc;
    __syncthreads();
    int woff = 0;
#pragma unroll
    for (int w = 0; w < 4; ++w)
        if (w < wid) woff += wsum[w];
    if (tid < nb) bsum[tid] = woff + sc - v;
    if (tid == 255) rowptr[n] = woff + sc;
}

__global__ void scan_add(int* __restrict__ rowptr, const int* __restrict__ bsum, int n) {
    int i = blockIdx.x * 256 + threadIdx.x;
    if (i < n) rowptr[i] += bsum[i >> 10];
}

// ---------------- CSR fill ----------------
__global__ void fill_kernel(const int* __restrict__ src, const int* __restrict__ dst,
                            const int* __restrict__ rowptr, int* __restrict__ fillcnt,
                            int* __restrict__ csr_src, int e) {
    int t = blockIdx.x * blockDim.x + threadIdx.x;
    if (t >= e) return;
    int d = dst[t];
    int pos = rowptr[d] + atomicAdd(&fillcnt[d], 1);
    csr_src[pos] = src[t];
}

// ---------------- GCN aggregate (bf16 gather, 8-unrolled) ----------------
__global__ __launch_bounds__(256) void gcn_agg_kernel(const unsigned short* __restrict__ hl, const float* __restrict__ dinv,
                                                      const int* __restrict__ rowptr, const int* __restrict__ csr_src,
                                                      const float* __restrict__ bias, float* __restrict__ out,
                                                      unsigned short* __restrict__ out_bf, int n) {
    int wave = threadIdx.x >> 6, lane = threadIdx.x & 63;
    int node = blockIdx.x * 4 + wave;
    if (node >= n) return;
    float dn = dinv[node];
    float2 sv = bf2_to_f2(((const unsigned int*)(hl + (size_t)node * 128))[lane]);
    float a0 = sv.x * dn * dn, a1 = sv.y * dn * dn;
    int beg = rowptr[node], end = rowptr[node + 1];
    int idx = beg;
    for (; idx + 8 <= end; idx += 8) {
        int s[8];
#pragma unroll
        for (int j = 0; j < 8; ++j) s[j] = csr_src[idx + j];
        unsigned int u[8];
        float w[8];
#pragma unroll
        for (int j = 0; j < 8; ++j) {
            u[j] = ((const unsigned int*)(hl + (size_t)s[j] * 128))[lane];
            w[j] = dinv[s[j]];
        }
#pragma unroll
        for (int j = 0; j < 8; ++j) {
            float2 h = bf2_to_f2(u[j]);
            float ww = w[j] * dn;
            a0 += h.x * ww;
            a1 += h.y * ww;
        }
    }
    for (; idx + 2 <= end; idx += 2) {
        int s0 = csr_src[idx], s1 = csr_src[idx + 1];
        unsigned int u0 = ((const unsigned int*)(hl + (size_t)s0 * 128))[lane];
        unsigned int u1 = ((const unsigned int*)(hl + (size_t)s1 * 128))[lane];
        float w0 = dinv[s0] * dn, w1 = dinv[s1] * dn;
        float2 h0 = bf2_to_f2(u0), h1 = bf2_to_f2(u1);
        a0 += h0.x * w0 + h1.x * w1;
        a1 += h0.y * w0 + h1.y * w1;
    }
    if (idx < end) {
        int s = csr_src[idx];
        float w = dinv[s] * dn;
        float2 h = bf2_to_f2(((const unsigned int*)(hl + (size_t)s * 128))[lane]);
        a0 += h.x * w;
        a1 += h.y * w;
    }
    int d0 = lane * 2;
    a0 = fmaxf(a0 + bias[d0], 0.f);
    a1 = fmaxf(a1 + bias[d0 + 1], 0.f);
    ((float2*)(out + (size_t)node * 128))[lane] = make_float2(a0, a1);
    ((unsigned int*)(out_bf + (size_t)node * 128))[lane] = (unsigned int)f2bf(a0) | ((unsigned int)f2bf(a1) << 16);
}

// ---------------- MLA attention: no-max softmax, 8-unrolled gather ----------------
__global__ __launch_bounds__(256) void attn_kernel(const float* __restrict__ q, const unsigned short* __restrict__ kv,
                                                   const int* __restrict__ rowptr, const int* __restrict__ csr_src,
                                                   unsigned short* __restrict__ agg_bf, int n) {
    int wave = threadIdx.x >> 6, lane = threadIdx.x & 63;
    int node = blockIdx.x * 4 + wave;
    if (node >= n) return;
    float2 qv = ((const float2*)(q + (size_t)node * 128))[lane];
    int beg = rowptr[node], end = rowptr[node + 1];
    float den = 0.f, a0 = 0.f, a1 = 0.f;
    int idx = beg;
    for (; idx + 8 <= end; idx += 8) {
        int s[8];
#pragma unroll
        for (int j = 0; j < 8; ++j) s[j] = csr_src[idx + j];
        unsigned int ku[8], vu[8];
#pragma unroll
        for (int j = 0; j < 8; ++j) {
            const unsigned int* r = (const unsigned int*)(kv + (size_t)s[j] * 256);
            ku[j] = r[lane];
            vu[j] = r[64 + lane];
        }
        float p[8];
#pragma unroll
        for (int j = 0; j < 8; ++j) {
            float2 k = bf2_to_f2(ku[j]);
            p[j] = qv.x * k.x + qv.y * k.y;
        }
#pragma unroll
        for (int j = 0; j < 8; ++j) p[j] += __shfl_xor(p[j], 1);
#pragma unroll
        for (int j = 0; j < 8; ++j) p[j] += __shfl_xor(p[j], 2);
#pragma unroll
        for (int j = 0; j < 8; ++j) p[j] += __shfl_xor(p[j], 4);
#pragma unroll
        for (int j = 0; j < 8; ++j) {
            float e = __expf(p[j] * 0.25f);
            float2 v = bf2_to_f2(vu[j]);
            den += e;
            a0 += e * v.x;
            a1 += e * v.y;
        }
    }
    for (; idx + 2 <= end; idx += 2) {
        int s0 = csr_src[idx], s1 = csr_src[idx + 1];
        const unsigned int* r0 = (const unsigned int*)(kv + (size_t)s0 * 256);
        const unsigned int* r1 = (const unsigned int*)(kv + (size_t)s1 * 256);
        unsigned int ku0 = r0[lane], vu0 = r0[64 + lane];
        unsigned int ku1 = r1[lane], vu1 = r1[64 + lane];
        float2 k0 = bf2_to_f2(ku0), k1 = bf2_to_f2(ku1);
        float p0 = qv.x * k0.x + qv.y * k0.y;
        float p1 = qv.x * k1.x + qv.y * k1.y;
        p0 += __shfl_xor(p0, 1); p1 += __shfl_xor(p1, 1);
        p0 += __shfl_xor(p0, 2); p1 += __shfl_xor(p1, 2);
        p0 += __shfl_xor(p0, 4); p1 += __shfl_xor(p1, 4);
        float e0 = __expf(p0 * 0.25f), e1 = __expf(p1 * 0.25f);
        den += e0 + e1;
        float2 v0 = bf2_to_f2(vu0), v1 = bf2_to_f2(vu1);
        a0 += e0 * v0.x + e1 * v1.x;
        a1 += e0 * v0.y + e1 * v1.y;
    }
    if (idx < end) {
        int s = csr_src[idx];
        const unsigned int* r = (const unsigned int*)(kv + (size_t)s * 256);
        unsigned int ku = r[lane], vu = r[64 + lane];
        float2 kvv = bf2_to_f2(ku);
        float p = qv.x * kvv.x + qv.y * kvv.y;
        p += __shfl_xor(p, 1);
        p += __shfl_xor(p, 2);
        p += __shfl_xor(p, 4);
        float e0 = __expf(p * 0.25f);
        den += e0;
        float2 vv = bf2_to_f2(vu);
        a0 += e0 * vv.x;
        a1 += e0 * vv.y;
    }
    float r = (end > beg) ? 1.f / fmaxf(den, 1e-16f) : 0.f;
    ((unsigned int*)(agg_bf + (size_t)node * 128))[lane] =
        (unsigned int)f2bf(a0 * r) | ((unsigned int)f2bf(a1 * r) << 16);
}

// ---------------- pool: one wave per graph, bounds via binary search ----------------
__global__ __launch_bounds__(256) void pool_kernel(const float* __restrict__ hF, const int* __restrict__ batch,
                                                   float* __restrict__ pooled, int n, int G) {
    int wave = threadIdx.x >> 6, lane = threadIdx.x & 63;
    int g = blockIdx.x * 4 + wave;
    if (g >= G) return;
    // lower_bound(batch, g) and lower_bound(batch, g+1) on sorted batch
    int lo = 0, hi = n;
    while (lo < hi) { int mid = (lo + hi) >> 1; if (batch[mid] < g) lo = mid + 1; else hi = mid; }
    int s = lo;
    hi = n;
    while (lo < hi) { int mid = (lo + hi) >> 1; if (batch[mid] < g + 1) lo = mid + 1; else hi = mid; }
    int e = lo;
    float a0 = 0.f, a1 = 0.f;
    for (int i = s; i < e; ++i) {
        float2 v = ((const float2*)(hF + (size_t)i * 128))[lane];
        a0 += v.x;
        a1 += v.y;
    }
    ((float2*)(pooled + (size_t)g * 128))[lane] = make_float2(a0, a1);
}

// ---------------- final FC ----------------
__global__ void fc_kernel(const float* __restrict__ pooled, const float* __restrict__ w,
                          const float* __restrict__ bias, float* __restrict__ out, int gcount) {
    int idx = blockIdx.x * blockDim.x + threadIdx.x;
    if (idx >= gcount * 19) return;
    int gi = idx / 19, j = idx % 19;
    float acc = bias[j];
#pragma unroll 8
    for (int k = 0; k < 128; ++k) acc += pooled[(size_t)gi * 128 + k] * w[k * 19 + j];
    out[idx] = acc;
}

extern "C" void kernel_launch(void* const* d_in, const int* in_sizes, int n_in,
                              void* d_out, int out_size, void* d_ws, size_t ws_size,
                              hipStream_t stream) {
    const int* x = (const int*)d_in[0];
    const int* edge_index = (const int*)d_in[1];
    const int* batch = (const int*)d_in[2];
    const float* node_emb = (const float*)d_in[3];
    const float* gcn_w = (const float*)d_in[4];
    const float* gcn_b = (const float*)d_in[5];
    const float* qd_w = (const float*)d_in[6];
    const float* qd_b = (const float*)d_in[7];
    const float* qu_w = (const float*)d_in[8];
    const float* qu_b = (const float*)d_in[9];
    const float* kvd_w = (const float*)d_in[10];
    const float* kvd_b = (const float*)d_in[11];
    const float* ku_w = (const float*)d_in[12];
    const float* ku_b = (const float*)d_in[13];
    const float* vu_w = (const float*)d_in[14];
    const float* vu_b = (const float*)d_in[15];
    const float* ow = (const float*)d_in[16];
    const float* ob = (const float*)d_in[17];
    const float* ln_g = (const float*)d_in[18];
    const float* ln_b = (const float*)d_in[19];
    const float* fc_w = (const float*)d_in[20];
    const float* fc_b = (const float*)d_in[21];
    float* out = (float*)d_out;

    const int N = in_sizes[0] / 11;
    const int E = in_sizes[1] / 2;
    const int G = out_size / 19;
    const int* esrc = edge_index;
    const int* edst = edge_index + E;

    char* ws = (char*)d_ws;
    auto carve = [&](size_t bytes) {
        void* p = (void*)ws;
        ws += WS_ALIGN(bytes);
        return p;
    };
    // weights (bf16 transposed)
    unsigned short* emb_bf = (unsigned short*)carve(12800 * 2);
    unsigned short* gcnw_t = (unsigned short*)carve(16384 * 2);
    unsigned short* ow_t = (unsigned short*)carve(16384 * 2);
    unsigned short* qkvd_t = (unsigned short*)carve(8192 * 2);
    unsigned short* quw_t = (unsigned short*)carve(4096 * 2);
    unsigned short* kvuw_t = (unsigned short*)carve(8192 * 2);
    float* qkv_bias = (float*)carve(64 * 4);
    float* kvu_bias = (float*)carve(256 * 4);
    // activations
    unsigned short* hB_bf = (unsigned short*)carve((size_t)N * 128 * 2);  // GCN-linear out
    float* hC = (float*)carve((size_t)N * 128 * 4);                        // residual (f32)
    unsigned short* hC_bf = (unsigned short*)carve((size_t)N * 128 * 2);  // qdkvd input
    float* q = (float*)carve((size_t)N * 128 * 4);                         // q; reused as hOut
    unsigned short* kv_bf = (unsigned short*)carve((size_t)N * 256 * 2);  // interleaved K|V
    float* dinv = (float*)carve((size_t)N * 4);
    int* cnt = (int*)carve((size_t)N * 4);
    int* fillcnt = (int*)carve((size_t)N * 4);
    int* rowptr = (int*)carve((size_t)(N + 1) * 4);
    int* bsum = (int*)carve(4096);
    int* csr_src = (int*)carve((size_t)E * 4);
    float* pooled = (float*)carve((size_t)G * 128 * 4);
    // aliases (stream-ordered lifetime-disjoint)
    float* qkv64 = (float*)hB_bf;              // N*64 f32 == N*128 bf16; hB_bf dead after gcn_agg
    unsigned short* agg_bf = hC_bf;            // hC_bf dead after qdkvd; agg written by attn
    float* hOut = q;                           // q dead after attn

    hipMemsetAsync(cnt, 0, (size_t)N * 4, stream);
    hipMemsetAsync(fillcnt, 0, (size_t)N * 4, stream);

    const int nb = (N + 1023) / 1024;
    const int gb = (N + 63) / 64;

    // 0. weight prep (bf16 transposed + biases)
    prep_kernel<<<260, 256, 0, stream>>>(node_emb, gcn_w, ow, qd_w, kvd_w, qu_w, ku_w, vu_w,
                                         qd_b, kvd_b, ku_b, vu_b,
                                         emb_bf, gcnw_t, ow_t, qkvd_t, quw_t, kvuw_t, qkv_bias, kvu_bias);

    // 1. GCN linear (embedding-gather A) -> hB_bf
    gemm_mfma<128, 128, 1><<<gb, 256, 0, stream>>>(nullptr, nullptr, x, emb_bf, 128, gcnw_t,
                                                   nullptr, hB_bf, nullptr, nullptr, nullptr, N);

    // 2. degree + CSR
    count_kernel<<<(E + 255) / 256, 256, 0, stream>>>(edst, cnt, E);
    scan_partial<<<nb, 256, 0, stream>>>(cnt, rowptr, bsum, dinv, N);
    scan_sums<<<1, 256, 0, stream>>>(bsum, rowptr, nb, N);
    scan_add<<<(N + 255) / 256, 256, 0, stream>>>(rowptr, bsum, N);
    fill_kernel<<<(E + 255) / 256, 256, 0, stream>>>(esrc, edst, rowptr, fillcnt, csr_src, E);

    // 3. GCN aggregate -> hC (f32) + hC_bf
    gcn_agg_kernel<<<(N + 3) / 4, 256, 0, stream>>>(hB_bf, dinv, rowptr, csr_src, gcn_b, hC, hC_bf, N);

    // 4. MLA projections (all MFMA)
    gemm_mfma<128, 64, 0><<<gb, 256, 0, stream>>>(hC_bf, nullptr, nullptr, nullptr, 128, qkvd_t,
                                                  qkv_bias, qkv64, nullptr, nullptr, nullptr, N);
    gemm_mfma<32, 128, 0><<<gb, 256, 0, stream>>>(nullptr, qkv64, nullptr, nullptr, 64, quw_t,
                                                  qu_b, q, nullptr, nullptr, nullptr, N);
    gemm_mfma<32, 256, 1><<<gb, 256, 0, stream>>>(nullptr, qkv64 + 32, nullptr, nullptr, 64, kvuw_t,
                                                  kvu_bias, kv_bf, nullptr, nullptr, nullptr, N);

    // 5. attention (no-max softmax, 8-unrolled) -> agg_bf
    attn_kernel<<<(N + 3) / 4, 256, 0, stream>>>(q, kv_bf, rowptr, csr_src, agg_bf, N);

    // 6. output projection + residual + LN + ReLU fused -> hOut
    gemm_mfma<128, 128, 2><<<gb, 256, 0, stream>>>(agg_bf, nullptr, nullptr, nullptr, 128, ow_t,
                                                   ob, hOut, hC, ln_g, ln_b, N);

    // 7. pool (binary-search bounds) + FC
    pool_kernel<<<(G + 3) / 4, 256, 0, stream>>>(hOut, batch, pooled, N, G);
    fc_kernel<<<(G * 19 + 255) / 256, 256, 0, stream>>>(pooled, fc_w, fc_b, out, G);
}